// Round 8
// baseline (229.107 us; speedup 1.0000x reference)
//
#include <hip/hip_runtime.h>
#include <cmath>

typedef unsigned short u16;
typedef __attribute__((ext_vector_type(8))) short bf16x8;
typedef __attribute__((ext_vector_type(4))) float f32x4;

#define BB    2
#define LSEQ  1024
#define DM    512
#define DI    1024
#define NTOK  2048   // BB*LSEQ
#define CL    16     // chunk length per lane (64 lanes * 16 = 1024 = LSEQ)

__device__ __forceinline__ float siluf(float x) {
    return x * (1.0f / (1.0f + __expf(-x)));
}
__device__ __forceinline__ float geluf(float x) {
    float c = 0.7978845608028654f * (x + 0.044715f * x * x * x);
    return 0.5f * x * (1.0f + tanhf(c));
}
__device__ __forceinline__ u16 f2bf(float f) {
    union { float f; unsigned u; } v; v.f = f;
    unsigned r = v.u + 0x7fff + ((v.u >> 16) & 1);
    return (u16)(r >> 16);
}
__device__ __forceinline__ float bf2f(u16 u) {
    union { unsigned u; float f; } v; v.u = ((unsigned)u) << 16; return v.f;
}
__device__ __forceinline__ void async_cp16(const u16* g, u16* l) {
    __builtin_amdgcn_global_load_lds(
        (const __attribute__((address_space(1))) void*)g,
        (__attribute__((address_space(3))) void*)l, 16, 0, 0);
}

#define NCVT 3680   // blocks for weight conversion (3768320 elems / 1024)

// ---------------- prep: weight bf16 conversion + LN1, one kernel ----------------
__global__ void prep_kernel(const float* __restrict__ s0, u16* __restrict__ d0,   // 1048576 in_proj
                            const float* __restrict__ s1, u16* __restrict__ d1,   // 524288  out_proj
                            const float* __restrict__ s2, u16* __restrict__ d2,   // 1048576 ffn1
                            const float* __restrict__ s3, u16* __restrict__ d3,   // 1048576 ffn2
                            const float* __restrict__ s4, u16* __restrict__ d4,   // 65536   x_proj
                            const float* __restrict__ s5, u16* __restrict__ d5,   // 32768   dt_proj
                            const float* __restrict__ x, const float* __restrict__ g,
                            const float* __restrict__ b, u16* __restrict__ lnb)
{
    __shared__ float shs[4], shq[4];
    __shared__ float smu, srs;
    if (blockIdx.x < NCVT) {
        int i = (blockIdx.x * 256 + threadIdx.x) * 4;
        const float* sp; u16* dp; int off;
        if      (i < 1048576) { sp = s0; dp = d0; off = i; }
        else if (i < 1572864) { sp = s1; dp = d1; off = i - 1048576; }
        else if (i < 2621440) { sp = s2; dp = d2; off = i - 1572864; }
        else if (i < 3670016) { sp = s3; dp = d3; off = i - 2621440; }
        else if (i < 3735552) { sp = s4; dp = d4; off = i - 3670016; }
        else                  { sp = s5; dp = d5; off = i - 3735552; }
        float4 v = *(const float4*)(sp + off);
        ushort4 o;
        o.x = f2bf(v.x); o.y = f2bf(v.y); o.z = f2bf(v.z); o.w = f2bf(v.w);
        *(ushort4*)(dp + off) = o;
        return;
    }
    // LayerNorm branch: token t
    int t = blockIdx.x - NCVT;
    int tid = threadIdx.x;
    const float* xr = x + (size_t)t * DM;
    float v0 = xr[tid];
    float v1 = xr[tid + 256];
    float rsum = v0 + v1;
    float rsq  = v0 * v0 + v1 * v1;
    #pragma unroll
    for (int o = 32; o > 0; o >>= 1) { rsum += __shfl_down(rsum, o); rsq += __shfl_down(rsq, o); }
    int wid = tid >> 6, lane = tid & 63;
    if (lane == 0) { shs[wid] = rsum; shq[wid] = rsq; }
    __syncthreads();
    if (tid == 0) {
        float a  = shs[0] + shs[1] + shs[2] + shs[3];
        float a2 = shq[0] + shq[1] + shq[2] + shq[3];
        float mu = a / DM;
        float var = a2 / DM - mu * mu;
        smu = mu;
        srs = rsqrtf(var + 1e-5f);
    }
    __syncthreads();
    float mu = smu, rs = srs;
    u16* orow = lnb + (size_t)t * DM;
    orow[tid]       = f2bf((v0 - mu) * rs * g[tid]       + b[tid]);
    orow[tid + 256] = f2bf((v1 - mu) * rs * g[tid + 256] + b[tid + 256]);
}

// ---------------- standalone LayerNorm (LN2) ----------------
__global__ void ln_bf16_kernel(const float* __restrict__ x, const float* __restrict__ g,
                               const float* __restrict__ b, u16* __restrict__ out)
{
    int t = blockIdx.x;
    int tid = threadIdx.x;
    const float* xr = x + (size_t)t * DM;
    float v0 = xr[tid];
    float v1 = xr[tid + 256];
    float rsum = v0 + v1;
    float rsq  = v0 * v0 + v1 * v1;
    #pragma unroll
    for (int o = 32; o > 0; o >>= 1) { rsum += __shfl_down(rsum, o); rsq += __shfl_down(rsq, o); }
    __shared__ float shs[4], shq[4];
    __shared__ float smu, srs;
    int wid = tid >> 6, lane = tid & 63;
    if (lane == 0) { shs[wid] = rsum; shq[wid] = rsq; }
    __syncthreads();
    if (tid == 0) {
        float a  = shs[0] + shs[1] + shs[2] + shs[3];
        float a2 = shq[0] + shq[1] + shq[2] + shq[3];
        float mu = a / DM;
        float var = a2 / DM - mu * mu;
        smu = mu;
        srs = rsqrtf(var + 1e-5f);
    }
    __syncthreads();
    float mu = smu, rs = srs;
    u16* orow = out + (size_t)t * DM;
    orow[tid]       = f2bf((v0 - mu) * rs * g[tid]       + b[tid]);
    orow[tid + 256] = f2bf((v1 - mu) * rs * g[tid + 256] + b[tid + 256]);
}

// ---------------- 4-wave MFMA GEMM (64 tiles). EPI: 0 plain, 3 +resid, 4 bias+resid ----------------
template<int EPI, int BM, int BN, int BK, int OBF>
__global__ __launch_bounds__(256)
void mgemm_kernel(const u16* __restrict__ A, const u16* __restrict__ W, int K,
                  void* __restrict__ Cp, int ldc,
                  const float* __restrict__ bias, const float* __restrict__ resid, int ldr)
{
    __shared__ u16 As[BM * BK];
    __shared__ u16 Bs[BN * BK];
    constexpr int WR = BM / 2, WC = BN / 2;
    constexpr int MR = WR / 16, NR = WC / 16;
    constexpr int LPR = BK / 8;
    constexpr int CH_ROWS = 64 / LPR;
    constexpr int NCH_A = BM / CH_ROWS, NCH_B = BN / CH_ROWS;

    const int tid = threadIdx.x;
    const int wave = tid >> 6, lane = tid & 63;
    const int wm = wave >> 1, wn = wave & 1;
    const int m0 = blockIdx.y * BM, n0 = blockIdx.x * BN;
    const int crow = lane / LPR, ckoff = (lane % LPR) * 8;
    const int fr = lane & 15;

    f32x4 acc[MR][NR] = {};

    for (int k0 = 0; k0 < K; k0 += BK) {
        for (int c = wave; c < NCH_A; c += 4)
            async_cp16(A + (size_t)(m0 + c * CH_ROWS + crow) * K + k0 + ckoff, &As[c * 512]);
        for (int c = wave; c < NCH_B; c += 4)
            async_cp16(W + (size_t)(n0 + c * CH_ROWS + crow) * K + k0 + ckoff, &Bs[c * 512]);
        __syncthreads();
        #pragma unroll
        for (int ks = 0; ks < BK / 32; ++ks) {
            const int fk = ks * 32 + ((lane >> 4) << 3);
            bf16x8 af[MR], bv[NR];
            #pragma unroll
            for (int i = 0; i < MR; ++i)
                af[i] = *(const bf16x8*)&As[(wm * WR + i * 16 + fr) * BK + fk];
            #pragma unroll
            for (int j = 0; j < NR; ++j)
                bv[j] = *(const bf16x8*)&Bs[(wn * WC + j * 16 + fr) * BK + fk];
            #pragma unroll
            for (int i = 0; i < MR; ++i)
                #pragma unroll
                for (int j = 0; j < NR; ++j)
                    acc[i][j] = __builtin_amdgcn_mfma_f32_16x16x32_bf16(af[i], bv[j], acc[i][j], 0, 0, 0);
        }
        __syncthreads();
    }

    const int rbase = (lane >> 4) << 2;
    #pragma unroll
    for (int i = 0; i < MR; ++i) {
        #pragma unroll
        for (int j = 0; j < NR; ++j) {
            const int col  = n0 + wn * WC + j * 16 + fr;
            const int row0 = m0 + wm * WR + i * 16 + rbase;
            float bvv = (EPI == 4) ? bias[col] : 0.0f;
            #pragma unroll
            for (int r = 0; r < 4; ++r) {
                float v = acc[i][j][r];
                if (EPI == 3) v += resid[(size_t)(row0 + r) * ldr + col];
                if (EPI == 4) v += bvv + resid[(size_t)(row0 + r) * ldr + col];
                if (OBF) ((u16*)Cp)[(size_t)(row0 + r) * ldc + col] = f2bf(v);
                else     ((float*)Cp)[(size_t)(row0 + r) * ldc + col] = v;
            }
        }
    }
}

// ---------------- 8-wave MFMA GEMM, 128x128 tile, BK=64 ----------------
template<int EPI, int OBF>
__global__ __launch_bounds__(512)
void mgemm8_kernel(const u16* __restrict__ A, const u16* __restrict__ W, int K,
                   void* __restrict__ Cp, int ldc, const float* __restrict__ bias)
{
    constexpr int BM = 128, BN = 128, BK = 64;
    __shared__ u16 As[BM * BK];
    __shared__ u16 Bs[BN * BK];
    const int tid = threadIdx.x;
    const int wave = tid >> 6, lane = tid & 63;
    const int wm = wave >> 2, wn = wave & 3;          // 2 x 4
    const int m0 = blockIdx.y * BM, n0 = blockIdx.x * BN;
    const int crow = lane >> 3, ckoff = (lane & 7) * 8;
    const int fr = lane & 15;

    f32x4 acc[4][2] = {};

    for (int k0 = 0; k0 < K; k0 += BK) {
        #pragma unroll
        for (int c = wave; c < 16; c += 8)
            async_cp16(A + (size_t)(m0 + c * 8 + crow) * K + k0 + ckoff, &As[c * 512]);
        #pragma unroll
        for (int c = wave; c < 16; c += 8)
            async_cp16(W + (size_t)(n0 + c * 8 + crow) * K + k0 + ckoff, &Bs[c * 512]);
        __syncthreads();
        #pragma unroll
        for (int ks = 0; ks < 2; ++ks) {
            const int fk = ks * 32 + ((lane >> 4) << 3);
            bf16x8 af[4], bv[2];
            #pragma unroll
            for (int i = 0; i < 4; ++i)
                af[i] = *(const bf16x8*)&As[(wm * 64 + i * 16 + fr) * BK + fk];
            #pragma unroll
            for (int j = 0; j < 2; ++j)
                bv[j] = *(const bf16x8*)&Bs[(wn * 32 + j * 16 + fr) * BK + fk];
            #pragma unroll
            for (int i = 0; i < 4; ++i)
                #pragma unroll
                for (int j = 0; j < 2; ++j)
                    acc[i][j] = __builtin_amdgcn_mfma_f32_16x16x32_bf16(af[i], bv[j], acc[i][j], 0, 0, 0);
        }
        __syncthreads();
    }

    const int rbase = (lane >> 4) << 2;
    #pragma unroll
    for (int i = 0; i < 4; ++i) {
        #pragma unroll
        for (int j = 0; j < 2; ++j) {
            const int col  = n0 + wn * 32 + j * 16 + fr;
            const int row0 = m0 + wm * 64 + i * 16 + rbase;
            float bvv = (EPI == 2) ? bias[col] : 0.0f;
            #pragma unroll
            for (int r = 0; r < 4; ++r) {
                float v = acc[i][j][r];
                if (EPI == 2) v = geluf(v + bvv);
                if (OBF) ((u16*)Cp)[(size_t)(row0 + r) * ldc + col] = f2bf(v);
                else     ((float*)Cp)[(size_t)(row0 + r) * ldc + col] = v;
            }
        }
    }
}

// ---------------- x_proj split-K MFMA: P[ks][2048][64] partials ----------------
__global__ __launch_bounds__(256)
void xproj_part_kernel(const u16* __restrict__ A, const u16* __restrict__ W,
                       float* __restrict__ P)
{
    constexpr int BM = 64, BK = 128;
    __shared__ u16 As[BM * BK];
    __shared__ u16 Bs[64 * BK];
    const int tid = threadIdx.x;
    const int wave = tid >> 6, lane = tid & 63;
    const int wm = wave >> 1, wn = wave & 1;
    const int ks = blockIdx.x;               // 0..7
    const int m0 = blockIdx.y * BM;
    const int k0 = ks * BK;
    const int crow = lane >> 4, ckoff = (lane & 15) * 8;
    const int fr = lane & 15;

    for (int c = wave; c < 16; c += 4) {
        async_cp16(A + (size_t)(m0 + c * 4 + crow) * 1024 + k0 + ckoff, &As[c * 512]);
        async_cp16(W + (size_t)(c * 4 + crow) * 1024 + k0 + ckoff, &Bs[c * 512]);
    }
    __syncthreads();

    f32x4 acc[2][2] = {};
    #pragma unroll
    for (int ks2 = 0; ks2 < 4; ++ks2) {
        const int fk = ks2 * 32 + ((lane >> 4) << 3);
        bf16x8 af[2], bv[2];
        #pragma unroll
        for (int i = 0; i < 2; ++i)
            af[i] = *(const bf16x8*)&As[(wm * 32 + i * 16 + fr) * BK + fk];
        #pragma unroll
        for (int j = 0; j < 2; ++j)
            bv[j] = *(const bf16x8*)&Bs[(wn * 32 + j * 16 + fr) * BK + fk];
        #pragma unroll
        for (int i = 0; i < 2; ++i)
            #pragma unroll
            for (int j = 0; j < 2; ++j)
                acc[i][j] = __builtin_amdgcn_mfma_f32_16x16x32_bf16(af[i], bv[j], acc[i][j], 0, 0, 0);
    }

    const int rbase = (lane >> 4) << 2;
    float* Pk = P + (size_t)ks * NTOK * 64;
    #pragma unroll
    for (int i = 0; i < 2; ++i)
        #pragma unroll
        for (int j = 0; j < 2; ++j) {
            const int col  = wn * 32 + j * 16 + fr;
            const int row0 = m0 + wm * 32 + i * 16 + rbase;
            #pragma unroll
            for (int r = 0; r < 4; ++r)
                Pk[(size_t)(row0 + r) * 64 + col] = acc[i][j][r];
        }
}

// reduce partials -> xdbl fp32 [2048,64]; also emit dt columns (0..31) as bf16 [2048,32]
__global__ void xproj_reduce_kernel(const float* __restrict__ P, float* __restrict__ xdbl,
                                    u16* __restrict__ dtb)
{
    int i = blockIdx.x * 256 + threadIdx.x;   // over 2048*64
    float s = 0.0f;
    #pragma unroll
    for (int ks = 0; ks < 8; ++ks) s += P[(size_t)ks * NTOK * 64 + i];
    xdbl[i] = s;
    int col = i & 63;
    if (col < 32) dtb[(i >> 6) * 32 + col] = f2bf(s);
}

// ---------------- depthwise causal conv1d (width 4) + SiLU; bf16 in/out, 8 ch/thread ----------------
__global__ void conv_silu_kernel(const u16* __restrict__ xz,
                                 const float* __restrict__ cw,
                                 const float* __restrict__ cb,
                                 u16* __restrict__ xcb)
{
    int idx = blockIdx.x * 256 + threadIdx.x;   // over NTOK*DI/8
    int e8 = idx & (DI / 8 - 1);
    int e  = e8 * 8;
    int t  = idx >> 7;
    int l  = t & (LSEQ - 1);
    const u16* base = xz + (size_t)t * 2048 + e;
    bf16x8 r0 = {}, r1 = {}, r2 = {}, r3;
    r3 = *(const bf16x8*)(base);
    if (l >= 1) r2 = *(const bf16x8*)(base - 2048);
    if (l >= 2) r1 = *(const bf16x8*)(base - 2 * 2048);
    if (l >= 3) r0 = *(const bf16x8*)(base - 3 * 2048);
    float o[8];
    #pragma unroll
    for (int j = 0; j < 8; ++j) {
        const float4 w = *(const float4*)(cw + (e + j) * 4);
        float acc = cb[e + j];
        acc = fmaf(bf2f((u16)r0[j]), w.x, acc);
        acc = fmaf(bf2f((u16)r1[j]), w.y, acc);
        acc = fmaf(bf2f((u16)r2[j]), w.z, acc);
        acc = fmaf(bf2f((u16)r3[j]), w.w, acc);
        o[j] = siluf(acc);
    }
    bf16x8 obf;
    #pragma unroll
    for (int j = 0; j < 8; ++j) obf[j] = (short)f2bf(o[j]);
    *(bf16x8*)(xcb + (size_t)t * DI + e) = obf;
}

// ============ fused selective scan: one wave per (b,e) ============
// lane c owns chunk c (CL=16 tokens). Phase 1: inline dt_proj+softplus, local scan
// from h=0. Phase 2: 6-step shfl_up affine scan over lanes -> entry states.
// Phase 3: replay with entry state, emit y = (scan + xc*D) * silu(z).
__global__ __launch_bounds__(256)
void scan_fused_kernel(const u16* __restrict__ dtb,      // [NTOK,32] bf16
                       const u16* __restrict__ wdt,      // [DI,32] bf16
                       const float* __restrict__ dt_bias,// [DI]
                       const u16* __restrict__ xcb,      // [NTOK,DI] bf16
                       const float* __restrict__ xdbl,   // [NTOK,64] (B@32, C@48)
                       const u16* __restrict__ xz,       // [NTOK,2048], z at +DI
                       const float* __restrict__ A_log,  // [DI,16]
                       const float* __restrict__ Dp,     // [DI]
                       u16* __restrict__ y)              // [NTOK,DI] bf16
{
    const int gw   = (blockIdx.x * 256 + threadIdx.x) >> 6;   // 0..2047
    const int lane = threadIdx.x & 63;
    const int b = gw >> 10;
    const int e = gw & (DI - 1);

    float Ae[16];
    #pragma unroll
    for (int n = 0; n < 16; ++n) Ae[n] = -__expf(A_log[e * 16 + n]);
    const float Dv = Dp[e];
    const float dbias = dt_bias[e];
    bf16x8 wv[4];
    #pragma unroll
    for (int q = 0; q < 4; ++q) wv[q] = *(const bf16x8*)(wdt + e * 32 + q * 8);

    const int t0 = b * LSEQ + lane * CL;

    // ---- phase 1: delta + xc into regs; local scan from h=0 ----
    float d[CL], xc[CL], h[16];
    #pragma unroll
    for (int n = 0; n < 16; ++n) h[n] = 0.0f;
    float sumd = 0.0f;
    #pragma unroll
    for (int l = 0; l < CL; ++l) {
        const size_t tok = (size_t)(t0 + l);
        float dt = dbias;
        const u16* dr = dtb + tok * 32;
        #pragma unroll
        for (int q = 0; q < 4; ++q) {
            bf16x8 dv = *(const bf16x8*)(dr + q * 8);
            #pragma unroll
            for (int k = 0; k < 8; ++k)
                dt = fmaf(bf2f((u16)dv[k]), bf2f((u16)wv[q][k]), dt);
        }
        float dd = (dt < 20.0f) ? log1pf(__expf(dt)) : dt;
        d[l] = dd;
        sumd += dd;
        float xcv = bf2f(xcb[tok * DI + e]);
        xc[l] = xcv;
        float dx = dd * xcv;
        const float4* B4 = (const float4*)(xdbl + tok * 64 + 32);
        #pragma unroll
        for (int q = 0; q < 4; ++q) {
            float4 Bq = B4[q];
            h[4*q+0] = __expf(dd * Ae[4*q+0]) * h[4*q+0] + dx * Bq.x;
            h[4*q+1] = __expf(dd * Ae[4*q+1]) * h[4*q+1] + dx * Bq.y;
            h[4*q+2] = __expf(dd * Ae[4*q+2]) * h[4*q+2] + dx * Bq.z;
            h[4*q+3] = __expf(dd * Ae[4*q+3]) * h[4*q+3] + dx * Bq.w;
        }
    }

    // ---- phase 2: wave affine scan (P = exp(Ae*sumd), q = h) -> entry states ----
    #pragma unroll
    for (int n = 0; n < 16; ++n) {
        float A  = __expf(Ae[n] * sumd);
        float Bv = h[n];
        #pragma unroll
        for (int off = 1; off < 64; off <<= 1) {
            float Ap = __shfl_up(A, off);
            float Bp = __shfl_up(Bv, off);
            if (lane >= off) { Bv = fmaf(A, Bp, Bv); A *= Ap; }
        }
        float pe = __shfl_up(Bv, 1);
        h[n] = (lane == 0) ? 0.0f : pe;   // entry state of this chunk
    }

    // ---- phase 3: replay with entry state, write y ----
    #pragma unroll
    for (int l = 0; l < CL; ++l) {
        const size_t tok = (size_t)(t0 + l);
        const float dd = d[l], xcv = xc[l];
        const float dx = dd * xcv;
        const float4* B4 = (const float4*)(xdbl + tok * 64 + 32);
        const float4* C4 = (const float4*)(xdbl + tok * 64 + 48);
        float yv = 0.0f;
        #pragma unroll
        for (int q = 0; q < 4; ++q) {
            float4 Bq = B4[q];
            float4 Cq = C4[q];
            float hb;
            hb = __expf(dd * Ae[4*q+0]) * h[4*q+0] + dx * Bq.x; h[4*q+0] = hb; yv = fmaf(hb, Cq.x, yv);
            hb = __expf(dd * Ae[4*q+1]) * h[4*q+1] + dx * Bq.y; h[4*q+1] = hb; yv = fmaf(hb, Cq.y, yv);
            hb = __expf(dd * Ae[4*q+2]) * h[4*q+2] + dx * Bq.z; h[4*q+2] = hb; yv = fmaf(hb, Cq.z, yv);
            hb = __expf(dd * Ae[4*q+3]) * h[4*q+3] + dx * Bq.w; h[4*q+3] = hb; yv = fmaf(hb, Cq.w, yv);
        }
        yv += xcv * Dv;
        yv *= siluf(bf2f(xz[tok * 2048 + DI + e]));
        y[tok * DI + e] = f2bf(yv);
    }
}

extern "C" void kernel_launch(void* const* d_in, const int* in_sizes, int n_in,
                              void* d_out, int out_size, void* d_ws, size_t ws_size,
                              hipStream_t stream)
{
    const float* x         = (const float*)d_in[0];
    const float* ln1_g     = (const float*)d_in[1];
    const float* ln1_b     = (const float*)d_in[2];
    const float* in_proj_w = (const float*)d_in[3];
    const float* conv_w    = (const float*)d_in[4];
    const float* conv_b    = (const float*)d_in[5];
    const float* x_proj_w  = (const float*)d_in[6];
    const float* dt_proj_w = (const float*)d_in[7];
    const float* dt_proj_b = (const float*)d_in[8];
    const float* A_log     = (const float*)d_in[9];
    const float* Dp        = (const float*)d_in[10];
    const float* out_proj_w= (const float*)d_in[11];
    const float* ln2_g     = (const float*)d_in[12];
    const float* ln2_b     = (const float*)d_in[13];
    const float* ffn1_w    = (const float*)d_in[14];
    const float* ffn1_b    = (const float*)d_in[15];
    const float* ffn2_w    = (const float*)d_in[16];
    const float* ffn2_b    = (const float*)d_in[17];
    float* out = (float*)d_out;

    // -------- workspace carve, no aliasing --------
    char* wsb = (char*)d_ws;
    u16*   lnb   = (u16*)wsb;    wsb += (size_t)2048 * 512 * 2;       // 2MB
    u16*   xzb   = (u16*)wsb;    wsb += (size_t)2048 * 2048 * 2;      // 8MB
    u16*   xcb   = (u16*)wsb;    wsb += (size_t)2048 * 1024 * 2;      // 4MB
    float* xdbl  = (float*)wsb;  wsb += (size_t)2048 * 64 * 4;        // 512KB
    u16*   dtb   = (u16*)wsb;    wsb += (size_t)2048 * 32 * 2;        // 128KB
    float* Ppart = (float*)wsb;  wsb += (size_t)8 * 2048 * 64 * 4;    // 4MB
    u16*   ybuf  = (u16*)wsb;    wsb += (size_t)2048 * 1024 * 2;      // 4MB
    float* x2    = (float*)wsb;  wsb += (size_t)2048 * 512 * 4;       // 4MB
    u16*   ffnm  = (u16*)wsb;    wsb += (size_t)2048 * 2048 * 2;      // 8MB
    u16*   w_in  = (u16*)wsb;    wsb += (size_t)2048 * 512 * 2;       // 2MB
    u16*   w_out = (u16*)wsb;    wsb += (size_t)512 * 1024 * 2;       // 1MB
    u16*   w_f1  = (u16*)wsb;    wsb += (size_t)2048 * 512 * 2;       // 2MB
    u16*   w_f2  = (u16*)wsb;    wsb += (size_t)512 * 2048 * 2;       // 2MB
    u16*   w_x   = (u16*)wsb;    wsb += (size_t)64 * 1024 * 2;        // 128KB
    u16*   w_dt  = (u16*)wsb;    wsb += (size_t)1024 * 32 * 2;        // 64KB

    // 0+1) weight conversions + LN1 (fused)
    prep_kernel<<<NCVT + NTOK, 256, 0, stream>>>(in_proj_w, w_in, out_proj_w, w_out,
                                                 ffn1_w, w_f1, ffn2_w, w_f2,
                                                 x_proj_w, w_x, dt_proj_w, w_dt,
                                                 x, ln1_g, ln1_b, lnb);
    // 2) in_proj MFMA 8-wave: [2048,512]x[2048,512]^T -> xz bf16 [2048,2048]
    mgemm8_kernel<0,1><<<dim3(16,16), 512, 0, stream>>>(lnb, w_in, 512, xzb, 2048, nullptr);
    // 3) conv + silu -> xcb bf16
    conv_silu_kernel<<<(NTOK * DI) / (256 * 8), 256, 0, stream>>>(xzb, conv_w, conv_b, xcb);
    // 4) x_proj split-K MFMA + reduce -> xdbl fp32 + dtb bf16
    xproj_part_kernel<<<dim3(8, 32), 256, 0, stream>>>(xcb, w_x, Ppart);
    xproj_reduce_kernel<<<(NTOK * 64) / 256, 256, 0, stream>>>(Ppart, xdbl, dtb);
    // 5) fused dt_proj + selective scan: one wave per (b,e)
    scan_fused_kernel<<<NTOK / 4, 256, 0, stream>>>(dtb, w_dt, dt_proj_b, xcb, xdbl,
                                                    xzb, A_log, Dp, ybuf);
    // 6) out_proj MFMA + residual(x): [2048,1024]x[512,1024]^T -> x2 fp32
    mgemm_kernel<3,64,64,128,0><<<dim3(8,32), 256, 0, stream>>>(ybuf, w_out, 1024, x2, 512, nullptr, x, 512);
    // 7) LN2 -> bf16
    ln_bf16_kernel<<<NTOK, 256, 0, stream>>>(x2, ln2_g, ln2_b, lnb);
    // 8) ffn1 MFMA 8-wave + bias + gelu -> ffn_mid bf16 [2048,2048]
    mgemm8_kernel<2,1><<<dim3(16,16), 512, 0, stream>>>(lnb, w_f1, 512, ffnm, 2048, ffn1_b);
    // 9) ffn2 MFMA + bias + residual(x2) -> out fp32
    mgemm_kernel<4,64,64,128,0><<<dim3(8,32), 256, 0, stream>>>(ffnm, w_f2, 2048, out, 512, ffn2_b, x2, 512);
}

// Round 9
// 171.652 us; speedup vs baseline: 1.3347x; 1.3347x over previous
//
#include <hip/hip_runtime.h>
#include <cmath>

typedef unsigned short u16;
typedef __attribute__((ext_vector_type(8))) short bf16x8;
typedef __attribute__((ext_vector_type(4))) float f32x4;

#define BB    2
#define LSEQ  1024
#define DM    512
#define DI    1024
#define NTOK  2048   // BB*LSEQ
#define NC    64     // chunks per sequence
#define CL    16     // chunk length

__device__ __forceinline__ float siluf(float x) {
    return x * (1.0f / (1.0f + __expf(-x)));
}
__device__ __forceinline__ float geluf(float x) {
    float c = 0.7978845608028654f * (x + 0.044715f * x * x * x);
    return 0.5f * x * (1.0f + tanhf(c));
}
__device__ __forceinline__ u16 f2bf(float f) {
    union { float f; unsigned u; } v; v.f = f;
    unsigned r = v.u + 0x7fff + ((v.u >> 16) & 1);
    return (u16)(r >> 16);
}
__device__ __forceinline__ float bf2f(u16 u) {
    union { unsigned u; float f; } v; v.u = ((unsigned)u) << 16; return v.f;
}
__device__ __forceinline__ void async_cp16(const u16* g, u16* l) {
    __builtin_amdgcn_global_load_lds(
        (const __attribute__((address_space(1))) void*)g,
        (__attribute__((address_space(3))) void*)l, 16, 0, 0);
}

#define NCVT 3680   // blocks for weight conversion (3768320 elems / 1024)

// ---------------- prep: weight bf16 conversion + LN1, one kernel ----------------
__global__ void prep_kernel(const float* __restrict__ s0, u16* __restrict__ d0,   // 1048576 in_proj
                            const float* __restrict__ s1, u16* __restrict__ d1,   // 524288  out_proj
                            const float* __restrict__ s2, u16* __restrict__ d2,   // 1048576 ffn1
                            const float* __restrict__ s3, u16* __restrict__ d3,   // 1048576 ffn2
                            const float* __restrict__ s4, u16* __restrict__ d4,   // 65536   x_proj
                            const float* __restrict__ s5, u16* __restrict__ d5,   // 32768   dt_proj
                            const float* __restrict__ x, const float* __restrict__ g,
                            const float* __restrict__ b, u16* __restrict__ lnb)
{
    __shared__ float shs[4], shq[4];
    __shared__ float smu, srs;
    if (blockIdx.x < NCVT) {
        int i = (blockIdx.x * 256 + threadIdx.x) * 4;
        const float* sp; u16* dp; int off;
        if      (i < 1048576) { sp = s0; dp = d0; off = i; }
        else if (i < 1572864) { sp = s1; dp = d1; off = i - 1048576; }
        else if (i < 2621440) { sp = s2; dp = d2; off = i - 1572864; }
        else if (i < 3670016) { sp = s3; dp = d3; off = i - 2621440; }
        else if (i < 3735552) { sp = s4; dp = d4; off = i - 3670016; }
        else                  { sp = s5; dp = d5; off = i - 3735552; }
        float4 v = *(const float4*)(sp + off);
        ushort4 o;
        o.x = f2bf(v.x); o.y = f2bf(v.y); o.z = f2bf(v.z); o.w = f2bf(v.w);
        *(ushort4*)(dp + off) = o;
        return;
    }
    // LayerNorm branch: token t
    int t = blockIdx.x - NCVT;
    int tid = threadIdx.x;
    const float* xr = x + (size_t)t * DM;
    float v0 = xr[tid];
    float v1 = xr[tid + 256];
    float rsum = v0 + v1;
    float rsq  = v0 * v0 + v1 * v1;
    #pragma unroll
    for (int o = 32; o > 0; o >>= 1) { rsum += __shfl_down(rsum, o); rsq += __shfl_down(rsq, o); }
    int wid = tid >> 6, lane = tid & 63;
    if (lane == 0) { shs[wid] = rsum; shq[wid] = rsq; }
    __syncthreads();
    if (tid == 0) {
        float a  = shs[0] + shs[1] + shs[2] + shs[3];
        float a2 = shq[0] + shq[1] + shq[2] + shq[3];
        float mu = a / DM;
        float var = a2 / DM - mu * mu;
        smu = mu;
        srs = rsqrtf(var + 1e-5f);
    }
    __syncthreads();
    float mu = smu, rs = srs;
    u16* orow = lnb + (size_t)t * DM;
    orow[tid]       = f2bf((v0 - mu) * rs * g[tid]       + b[tid]);
    orow[tid + 256] = f2bf((v1 - mu) * rs * g[tid + 256] + b[tid + 256]);
}

// ---------------- standalone LayerNorm (LN2) ----------------
__global__ void ln_bf16_kernel(const float* __restrict__ x, const float* __restrict__ g,
                               const float* __restrict__ b, u16* __restrict__ out)
{
    int t = blockIdx.x;
    int tid = threadIdx.x;
    const float* xr = x + (size_t)t * DM;
    float v0 = xr[tid];
    float v1 = xr[tid + 256];
    float rsum = v0 + v1;
    float rsq  = v0 * v0 + v1 * v1;
    #pragma unroll
    for (int o = 32; o > 0; o >>= 1) { rsum += __shfl_down(rsum, o); rsq += __shfl_down(rsq, o); }
    __shared__ float shs[4], shq[4];
    __shared__ float smu, srs;
    int wid = tid >> 6, lane = tid & 63;
    if (lane == 0) { shs[wid] = rsum; shq[wid] = rsq; }
    __syncthreads();
    if (tid == 0) {
        float a  = shs[0] + shs[1] + shs[2] + shs[3];
        float a2 = shq[0] + shq[1] + shq[2] + shq[3];
        float mu = a / DM;
        float var = a2 / DM - mu * mu;
        smu = mu;
        srs = rsqrtf(var + 1e-5f);
    }
    __syncthreads();
    float mu = smu, rs = srs;
    u16* orow = out + (size_t)t * DM;
    orow[tid]       = f2bf((v0 - mu) * rs * g[tid]       + b[tid]);
    orow[tid + 256] = f2bf((v1 - mu) * rs * g[tid + 256] + b[tid + 256]);
}

// ---------------- 4-wave MFMA GEMM (64 tiles). EPI: 3 +resid, 4 bias+resid ----------------
template<int EPI, int BM, int BN, int BK, int OBF>
__global__ __launch_bounds__(256)
void mgemm_kernel(const u16* __restrict__ A, const u16* __restrict__ W, int K,
                  void* __restrict__ Cp, int ldc,
                  const float* __restrict__ bias, const float* __restrict__ resid, int ldr)
{
    __shared__ u16 As[BM * BK];
    __shared__ u16 Bs[BN * BK];
    constexpr int WR = BM / 2, WC = BN / 2;
    constexpr int MR = WR / 16, NR = WC / 16;
    constexpr int LPR = BK / 8;
    constexpr int CH_ROWS = 64 / LPR;
    constexpr int NCH_A = BM / CH_ROWS, NCH_B = BN / CH_ROWS;

    const int tid = threadIdx.x;
    const int wave = tid >> 6, lane = tid & 63;
    const int wm = wave >> 1, wn = wave & 1;
    const int m0 = blockIdx.y * BM, n0 = blockIdx.x * BN;
    const int crow = lane / LPR, ckoff = (lane % LPR) * 8;
    const int fr = lane & 15;

    f32x4 acc[MR][NR] = {};

    for (int k0 = 0; k0 < K; k0 += BK) {
        for (int c = wave; c < NCH_A; c += 4)
            async_cp16(A + (size_t)(m0 + c * CH_ROWS + crow) * K + k0 + ckoff, &As[c * 512]);
        for (int c = wave; c < NCH_B; c += 4)
            async_cp16(W + (size_t)(n0 + c * CH_ROWS + crow) * K + k0 + ckoff, &Bs[c * 512]);
        __syncthreads();
        #pragma unroll
        for (int ks = 0; ks < BK / 32; ++ks) {
            const int fk = ks * 32 + ((lane >> 4) << 3);
            bf16x8 af[MR], bv[NR];
            #pragma unroll
            for (int i = 0; i < MR; ++i)
                af[i] = *(const bf16x8*)&As[(wm * WR + i * 16 + fr) * BK + fk];
            #pragma unroll
            for (int j = 0; j < NR; ++j)
                bv[j] = *(const bf16x8*)&Bs[(wn * WC + j * 16 + fr) * BK + fk];
            #pragma unroll
            for (int i = 0; i < MR; ++i)
                #pragma unroll
                for (int j = 0; j < NR; ++j)
                    acc[i][j] = __builtin_amdgcn_mfma_f32_16x16x32_bf16(af[i], bv[j], acc[i][j], 0, 0, 0);
        }
        __syncthreads();
    }

    const int rbase = (lane >> 4) << 2;
    #pragma unroll
    for (int i = 0; i < MR; ++i) {
        #pragma unroll
        for (int j = 0; j < NR; ++j) {
            const int col  = n0 + wn * WC + j * 16 + fr;
            const int row0 = m0 + wm * WR + i * 16 + rbase;
            float bvv = (EPI == 4) ? bias[col] : 0.0f;
            #pragma unroll
            for (int r = 0; r < 4; ++r) {
                float v = acc[i][j][r];
                if (EPI == 3) v += resid[(size_t)(row0 + r) * ldr + col];
                if (EPI == 4) v += bvv + resid[(size_t)(row0 + r) * ldr + col];
                if (OBF) ((u16*)Cp)[(size_t)(row0 + r) * ldc + col] = f2bf(v);
                else     ((float*)Cp)[(size_t)(row0 + r) * ldc + col] = v;
            }
        }
    }
}

// ---------------- 8-wave MFMA GEMM, 128x128 tile, BK=64 ----------------
template<int EPI, int OBF>
__global__ __launch_bounds__(512)
void mgemm8_kernel(const u16* __restrict__ A, const u16* __restrict__ W, int K,
                   void* __restrict__ Cp, int ldc, const float* __restrict__ bias)
{
    constexpr int BM = 128, BN = 128, BK = 64;
    __shared__ u16 As[BM * BK];
    __shared__ u16 Bs[BN * BK];
    const int tid = threadIdx.x;
    const int wave = tid >> 6, lane = tid & 63;
    const int wm = wave >> 2, wn = wave & 3;          // 2 x 4
    const int m0 = blockIdx.y * BM, n0 = blockIdx.x * BN;
    const int crow = lane >> 3, ckoff = (lane & 7) * 8;
    const int fr = lane & 15;

    f32x4 acc[4][2] = {};

    for (int k0 = 0; k0 < K; k0 += BK) {
        #pragma unroll
        for (int c = wave; c < 16; c += 8)
            async_cp16(A + (size_t)(m0 + c * 8 + crow) * K + k0 + ckoff, &As[c * 512]);
        #pragma unroll
        for (int c = wave; c < 16; c += 8)
            async_cp16(W + (size_t)(n0 + c * 8 + crow) * K + k0 + ckoff, &Bs[c * 512]);
        __syncthreads();
        #pragma unroll
        for (int ks = 0; ks < 2; ++ks) {
            const int fk = ks * 32 + ((lane >> 4) << 3);
            bf16x8 af[4], bv[2];
            #pragma unroll
            for (int i = 0; i < 4; ++i)
                af[i] = *(const bf16x8*)&As[(wm * 64 + i * 16 + fr) * BK + fk];
            #pragma unroll
            for (int j = 0; j < 2; ++j)
                bv[j] = *(const bf16x8*)&Bs[(wn * 32 + j * 16 + fr) * BK + fk];
            #pragma unroll
            for (int i = 0; i < 4; ++i)
                #pragma unroll
                for (int j = 0; j < 2; ++j)
                    acc[i][j] = __builtin_amdgcn_mfma_f32_16x16x32_bf16(af[i], bv[j], acc[i][j], 0, 0, 0);
        }
        __syncthreads();
    }

    const int rbase = (lane >> 4) << 2;
    #pragma unroll
    for (int i = 0; i < 4; ++i) {
        #pragma unroll
        for (int j = 0; j < 2; ++j) {
            const int col  = n0 + wn * 32 + j * 16 + fr;
            const int row0 = m0 + wm * 64 + i * 16 + rbase;
            float bvv = (EPI == 2) ? bias[col] : 0.0f;
            #pragma unroll
            for (int r = 0; r < 4; ++r) {
                float v = acc[i][j][r];
                if (EPI == 2) v = geluf(v + bvv);
                if (OBF) ((u16*)Cp)[(size_t)(row0 + r) * ldc + col] = f2bf(v);
                else     ((float*)Cp)[(size_t)(row0 + r) * ldc + col] = v;
            }
        }
    }
}

// ---------------- x_proj split-K MFMA: P[ks][2048][64] partials ----------------
__global__ __launch_bounds__(256)
void xproj_part_kernel(const u16* __restrict__ A, const u16* __restrict__ W,
                       float* __restrict__ P)
{
    constexpr int BM = 64, BK = 128;
    __shared__ u16 As[BM * BK];
    __shared__ u16 Bs[64 * BK];
    const int tid = threadIdx.x;
    const int wave = tid >> 6, lane = tid & 63;
    const int wm = wave >> 1, wn = wave & 1;
    const int ks = blockIdx.x;               // 0..7
    const int m0 = blockIdx.y * BM;
    const int k0 = ks * BK;
    const int crow = lane >> 4, ckoff = (lane & 15) * 8;
    const int fr = lane & 15;

    for (int c = wave; c < 16; c += 4) {
        async_cp16(A + (size_t)(m0 + c * 4 + crow) * 1024 + k0 + ckoff, &As[c * 512]);
        async_cp16(W + (size_t)(c * 4 + crow) * 1024 + k0 + ckoff, &Bs[c * 512]);
    }
    __syncthreads();

    f32x4 acc[2][2] = {};
    #pragma unroll
    for (int ks2 = 0; ks2 < 4; ++ks2) {
        const int fk = ks2 * 32 + ((lane >> 4) << 3);
        bf16x8 af[2], bv[2];
        #pragma unroll
        for (int i = 0; i < 2; ++i)
            af[i] = *(const bf16x8*)&As[(wm * 32 + i * 16 + fr) * BK + fk];
        #pragma unroll
        for (int j = 0; j < 2; ++j)
            bv[j] = *(const bf16x8*)&Bs[(wn * 32 + j * 16 + fr) * BK + fk];
        #pragma unroll
        for (int i = 0; i < 2; ++i)
            #pragma unroll
            for (int j = 0; j < 2; ++j)
                acc[i][j] = __builtin_amdgcn_mfma_f32_16x16x32_bf16(af[i], bv[j], acc[i][j], 0, 0, 0);
    }

    const int rbase = (lane >> 4) << 2;
    float* Pk = P + (size_t)ks * NTOK * 64;
    #pragma unroll
    for (int i = 0; i < 2; ++i)
        #pragma unroll
        for (int j = 0; j < 2; ++j) {
            const int col  = wn * 32 + j * 16 + fr;
            const int row0 = m0 + wm * 32 + i * 16 + rbase;
            #pragma unroll
            for (int r = 0; r < 4; ++r)
                Pk[(size_t)(row0 + r) * 64 + col] = acc[i][j][r];
        }
}

// reduce partials -> xdbl fp32 [2048,64]; also emit dt columns (0..31) as bf16 [2048,32]
__global__ void xproj_reduce_kernel(const float* __restrict__ P, float* __restrict__ xdbl,
                                    u16* __restrict__ dtb)
{
    int i = blockIdx.x * 256 + threadIdx.x;   // over 2048*64
    float s = 0.0f;
    #pragma unroll
    for (int ks = 0; ks < 8; ++ks) s += P[(size_t)ks * NTOK * 64 + i];
    xdbl[i] = s;
    int col = i & 63;
    if (col < 32) dtb[(i >> 6) * 32 + col] = f2bf(s);
}

// ---------------- depthwise causal conv1d (width 4) + SiLU; bf16 in/out, 8 ch/thread ----------------
__global__ void conv_silu_kernel(const u16* __restrict__ xz,
                                 const float* __restrict__ cw,
                                 const float* __restrict__ cb,
                                 u16* __restrict__ xcb)
{
    int idx = blockIdx.x * 256 + threadIdx.x;   // over NTOK*DI/8
    int e8 = idx & (DI / 8 - 1);
    int e  = e8 * 8;
    int t  = idx >> 7;
    int l  = t & (LSEQ - 1);
    const u16* base = xz + (size_t)t * 2048 + e;
    bf16x8 r0 = {}, r1 = {}, r2 = {}, r3;
    r3 = *(const bf16x8*)(base);
    if (l >= 1) r2 = *(const bf16x8*)(base - 2048);
    if (l >= 2) r1 = *(const bf16x8*)(base - 2 * 2048);
    if (l >= 3) r0 = *(const bf16x8*)(base - 3 * 2048);
    float o[8];
    #pragma unroll
    for (int j = 0; j < 8; ++j) {
        const float4 w = *(const float4*)(cw + (e + j) * 4);
        float acc = cb[e + j];
        acc = fmaf(bf2f((u16)r0[j]), w.x, acc);
        acc = fmaf(bf2f((u16)r1[j]), w.y, acc);
        acc = fmaf(bf2f((u16)r2[j]), w.z, acc);
        acc = fmaf(bf2f((u16)r3[j]), w.w, acc);
        o[j] = siluf(acc);
    }
    bf16x8 obf;
    #pragma unroll
    for (int j = 0; j < 8; ++j) obf[j] = (short)f2bf(o[j]);
    *(bf16x8*)(xcb + (size_t)t * DI + e) = obf;
}

// ---- inline dt_proj + softplus: delta for one (tok, e). dtb row is wave-uniform ----
__device__ __forceinline__ float delta_of(const u16* __restrict__ dtb, size_t tok,
                                          const bf16x8* wv, float dbias)
{
    float dt = dbias;
    const u16* dr = dtb + tok * 32;
    #pragma unroll
    for (int q = 0; q < 4; ++q) {
        bf16x8 dv = *(const bf16x8*)(dr + q * 8);
        #pragma unroll
        for (int k = 0; k < 8; ++k)
            dt = fmaf(bf2f((u16)dv[k]), bf2f((u16)wv[q][k]), dt);
    }
    return (dt < 20.0f) ? log1pf(__expf(dt)) : dt;
}

// ============ chunked selective scan (NC=64, CL=16); dt_proj inlined ============
__global__ void scanA_kernel(const u16* __restrict__ dtb,
                             const u16* __restrict__ wdt,
                             const float* __restrict__ dt_bias,
                             const u16* __restrict__ xcb,
                             const float* __restrict__ xdbl,
                             const float* __restrict__ A_log,
                             float* __restrict__ qbuf,
                             float* __restrict__ sumd)
{
    int i = blockIdx.x * 256 + threadIdx.x;   // ((b*NC + c) << 10) | e
    int e = i & (DI - 1);
    int c = (i >> 10) & (NC - 1);
    int b = i >> 16;
    float Ae[16], h[16];
    #pragma unroll
    for (int n = 0; n < 16; ++n) { Ae[n] = -__expf(A_log[e * 16 + n]); h[n] = 0.0f; }
    const float dbias = dt_bias[e];
    bf16x8 wv[4];
    #pragma unroll
    for (int q = 0; q < 4; ++q) wv[q] = *(const bf16x8*)(wdt + e * 32 + q * 8);
    float sd = 0.0f;
    int l0 = c * CL;
    for (int l = 0; l < CL; ++l) {
        size_t tok = (size_t)b * LSEQ + l0 + l;
        float d = delta_of(dtb, tok, wv, dbias);
        float xcv = bf2f(xcb[tok * DI + e]);
        sd += d;
        float dx = d * xcv;
        const float4* B4 = (const float4*)(xdbl + tok * 64 + 32);
        #pragma unroll
        for (int q = 0; q < 4; ++q) {
            float4 Bq = B4[q];
            h[4*q+0] = __expf(d * Ae[4*q+0]) * h[4*q+0] + dx * Bq.x;
            h[4*q+1] = __expf(d * Ae[4*q+1]) * h[4*q+1] + dx * Bq.y;
            h[4*q+2] = __expf(d * Ae[4*q+2]) * h[4*q+2] + dx * Bq.z;
            h[4*q+3] = __expf(d * Ae[4*q+3]) * h[4*q+3] + dx * Bq.w;
        }
    }
    size_t base = ((size_t)(b * DI + e) * NC + c) * 16;
    #pragma unroll
    for (int n = 0; n < 16; ++n) qbuf[base + n] = h[n];
    sumd[(size_t)(b * DI + e) * NC + c] = sd;
}

__global__ void scanB_kernel(const float* __restrict__ qbuf,
                             const float* __restrict__ sumd,
                             const float* __restrict__ A_log,
                             float* __restrict__ hin)
{
    int i = blockIdx.x * 256 + threadIdx.x;   // ((b<<10)|e)<<4 | n
    int n = i & 15;
    int e = (i >> 4) & (DI - 1);
    int b = i >> 14;
    float Ae = -__expf(A_log[e * 16 + n]);
    float h = 0.0f;
    size_t base = (size_t)(b * DI + e) * NC;
    for (int c = 0; c < NC; ++c) {
        hin[(base + c) * 16 + n] = h;
        float P = __expf(Ae * sumd[base + c]);
        h = P * h + qbuf[(base + c) * 16 + n];
    }
}

// Pass C: replay from entry state; y (bf16) = (scan + xc*D) * silu(z)
__global__ void scanC_kernel(const u16* __restrict__ dtb,
                             const u16* __restrict__ wdt,
                             const float* __restrict__ dt_bias,
                             const u16* __restrict__ xcb,
                             const float* __restrict__ xdbl,
                             const u16* __restrict__ xz,
                             const float* __restrict__ A_log,
                             const float* __restrict__ Dp,
                             const float* __restrict__ hin,
                             u16* __restrict__ y)
{
    int i = blockIdx.x * 256 + threadIdx.x;
    int e = i & (DI - 1);
    int c = (i >> 10) & (NC - 1);
    int b = i >> 16;
    float Ae[16], h[16];
    size_t base = ((size_t)(b * DI + e) * NC + c) * 16;
    #pragma unroll
    for (int n = 0; n < 16; ++n) {
        Ae[n] = -__expf(A_log[e * 16 + n]);
        h[n] = hin[base + n];
    }
    const float dbias = dt_bias[e];
    bf16x8 wv[4];
    #pragma unroll
    for (int q = 0; q < 4; ++q) wv[q] = *(const bf16x8*)(wdt + e * 32 + q * 8);
    float Dv = Dp[e];
    int l0 = c * CL;
    for (int l = 0; l < CL; ++l) {
        size_t tok = (size_t)b * LSEQ + l0 + l;
        float d = delta_of(dtb, tok, wv, dbias);
        float xcv = bf2f(xcb[tok * DI + e]);
        float zv  = bf2f(xz[tok * 2048 + DI + e]);
        float dx = d * xcv;
        const float4* B4 = (const float4*)(xdbl + tok * 64 + 32);
        const float4* C4 = (const float4*)(xdbl + tok * 64 + 48);
        float yv = 0.0f;
        #pragma unroll
        for (int q = 0; q < 4; ++q) {
            float4 Bq = B4[q];
            float4 Cq = C4[q];
            float hb;
            hb = __expf(d * Ae[4*q+0]) * h[4*q+0] + dx * Bq.x; h[4*q+0] = hb; yv = fmaf(hb, Cq.x, yv);
            hb = __expf(d * Ae[4*q+1]) * h[4*q+1] + dx * Bq.y; h[4*q+1] = hb; yv = fmaf(hb, Cq.y, yv);
            hb = __expf(d * Ae[4*q+2]) * h[4*q+2] + dx * Bq.z; h[4*q+2] = hb; yv = fmaf(hb, Cq.z, yv);
            hb = __expf(d * Ae[4*q+3]) * h[4*q+3] + dx * Bq.w; h[4*q+3] = hb; yv = fmaf(hb, Cq.w, yv);
        }
        yv += xcv * Dv;
        yv *= siluf(zv);
        y[tok * DI + e] = f2bf(yv);
    }
}

extern "C" void kernel_launch(void* const* d_in, const int* in_sizes, int n_in,
                              void* d_out, int out_size, void* d_ws, size_t ws_size,
                              hipStream_t stream)
{
    const float* x         = (const float*)d_in[0];
    const float* ln1_g     = (const float*)d_in[1];
    const float* ln1_b     = (const float*)d_in[2];
    const float* in_proj_w = (const float*)d_in[3];
    const float* conv_w    = (const float*)d_in[4];
    const float* conv_b    = (const float*)d_in[5];
    const float* x_proj_w  = (const float*)d_in[6];
    const float* dt_proj_w = (const float*)d_in[7];
    const float* dt_proj_b = (const float*)d_in[8];
    const float* A_log     = (const float*)d_in[9];
    const float* Dp        = (const float*)d_in[10];
    const float* out_proj_w= (const float*)d_in[11];
    const float* ln2_g     = (const float*)d_in[12];
    const float* ln2_b     = (const float*)d_in[13];
    const float* ffn1_w    = (const float*)d_in[14];
    const float* ffn1_b    = (const float*)d_in[15];
    const float* ffn2_w    = (const float*)d_in[16];
    const float* ffn2_b    = (const float*)d_in[17];
    float* out = (float*)d_out;

    // -------- workspace carve, no aliasing --------
    char* wsb = (char*)d_ws;
    u16*   lnb   = (u16*)wsb;    wsb += (size_t)2048 * 512 * 2;       // 2MB
    u16*   xzb   = (u16*)wsb;    wsb += (size_t)2048 * 2048 * 2;      // 8MB
    u16*   xcb   = (u16*)wsb;    wsb += (size_t)2048 * 1024 * 2;      // 4MB
    float* xdbl  = (float*)wsb;  wsb += (size_t)2048 * 64 * 4;        // 512KB
    u16*   dtb   = (u16*)wsb;    wsb += (size_t)2048 * 32 * 2;        // 128KB
    float* Ppart = (float*)wsb;  wsb += (size_t)8 * 2048 * 64 * 4;    // 4MB
    float* qbuf  = (float*)wsb;  wsb += (size_t)2048 * NC * 16 * 4;   // 8MB
    float* sumd  = (float*)wsb;  wsb += (size_t)BB * DI * NC * 4;     // 512KB
    float* hin   = (float*)wsb;  wsb += (size_t)2048 * NC * 16 * 4;   // 8MB
    u16*   ybuf  = (u16*)wsb;    wsb += (size_t)2048 * 1024 * 2;      // 4MB
    float* x2    = (float*)wsb;  wsb += (size_t)2048 * 512 * 4;       // 4MB
    u16*   ffnm  = (u16*)wsb;    wsb += (size_t)2048 * 2048 * 2;      // 8MB
    u16*   w_in  = (u16*)wsb;    wsb += (size_t)2048 * 512 * 2;       // 2MB
    u16*   w_out = (u16*)wsb;    wsb += (size_t)512 * 1024 * 2;       // 1MB
    u16*   w_f1  = (u16*)wsb;    wsb += (size_t)2048 * 512 * 2;       // 2MB
    u16*   w_f2  = (u16*)wsb;    wsb += (size_t)512 * 2048 * 2;       // 2MB
    u16*   w_x   = (u16*)wsb;    wsb += (size_t)64 * 1024 * 2;        // 128KB
    u16*   w_dt  = (u16*)wsb;    wsb += (size_t)1024 * 32 * 2;        // 64KB

    // 0+1) weight conversions + LN1 (fused)
    prep_kernel<<<NCVT + NTOK, 256, 0, stream>>>(in_proj_w, w_in, out_proj_w, w_out,
                                                 ffn1_w, w_f1, ffn2_w, w_f2,
                                                 x_proj_w, w_x, dt_proj_w, w_dt,
                                                 x, ln1_g, ln1_b, lnb);
    // 2) in_proj MFMA 8-wave: [2048,512]x[2048,512]^T -> xz bf16 [2048,2048]
    mgemm8_kernel<0,1><<<dim3(16,16), 512, 0, stream>>>(lnb, w_in, 512, xzb, 2048, nullptr);
    // 3) conv + silu -> xcb bf16
    conv_silu_kernel<<<(NTOK * DI) / (256 * 8), 256, 0, stream>>>(xzb, conv_w, conv_b, xcb);
    // 4) x_proj split-K MFMA + reduce -> xdbl fp32 + dtb bf16
    xproj_part_kernel<<<dim3(8, 32), 256, 0, stream>>>(xcb, w_x, Ppart);
    xproj_reduce_kernel<<<(NTOK * 64) / 256, 256, 0, stream>>>(Ppart, xdbl, dtb);
    // 5) chunked scan, dt_proj inlined (NC=64, CL=16)
    scanA_kernel<<<(BB * NC * DI) / 256, 256, 0, stream>>>(dtb, w_dt, dt_proj_b, xcb, xdbl, A_log, qbuf, sumd);
    scanB_kernel<<<(BB * DI * 16) / 256, 256, 0, stream>>>(qbuf, sumd, A_log, hin);
    scanC_kernel<<<(BB * NC * DI) / 256, 256, 0, stream>>>(dtb, w_dt, dt_proj_b, xcb, xdbl, xzb, A_log, Dp, hin, ybuf);
    // 6) out_proj MFMA + residual(x): [2048,1024]x[512,1024]^T -> x2 fp32
    mgemm_kernel<3,64,64,128,0><<<dim3(8,32), 256, 0, stream>>>(ybuf, w_out, 1024, x2, 512, nullptr, x, 512);
    // 7) LN2 -> bf16
    ln_bf16_kernel<<<NTOK, 256, 0, stream>>>(x2, ln2_g, ln2_b, lnb);
    // 8) ffn1 MFMA 8-wave + bias + gelu -> ffn_mid bf16 [2048,2048]
    mgemm8_kernel<2,1><<<dim3(16,16), 512, 0, stream>>>(lnb, w_f1, 512, ffnm, 2048, ffn1_b);
    // 9) ffn2 MFMA + bias + residual(x2) -> out fp32
    mgemm_kernel<4,64,64,128,0><<<dim3(8,32), 256, 0, stream>>>(ffnm, w_f2, 2048, out, 512, ffn2_b, x2, 512);
}

// Round 10
// 171.204 us; speedup vs baseline: 1.3382x; 1.0026x over previous
//
#include <hip/hip_runtime.h>
#include <cmath>

typedef unsigned short u16;
typedef __attribute__((ext_vector_type(8))) short bf16x8;
typedef __attribute__((ext_vector_type(4))) float f32x4;

#define BB    2
#define LSEQ  1024
#define DM    512
#define DI    1024
#define NTOK  2048   // BB*LSEQ
#define NC    64     // chunks per sequence
#define CL    16     // chunk length

__device__ __forceinline__ float siluf(float x) {
    return x * (1.0f / (1.0f + __expf(-x)));
}
__device__ __forceinline__ float geluf(float x) {
    float c = 0.7978845608028654f * (x + 0.044715f * x * x * x);
    return 0.5f * x * (1.0f + tanhf(c));
}
__device__ __forceinline__ u16 f2bf(float f) {
    union { float f; unsigned u; } v; v.f = f;
    unsigned r = v.u + 0x7fff + ((v.u >> 16) & 1);
    return (u16)(r >> 16);
}
__device__ __forceinline__ float bf2f(u16 u) {
    union { unsigned u; float f; } v; v.u = ((unsigned)u) << 16; return v.f;
}
__device__ __forceinline__ void async_cp16(const u16* g, u16* l) {
    __builtin_amdgcn_global_load_lds(
        (const __attribute__((address_space(1))) void*)g,
        (__attribute__((address_space(3))) void*)l, 16, 0, 0);
}

#define NCVT 3680   // blocks for weight conversion (3768320 elems / 1024)

// ---------------- prep: weight bf16 conversion + LN1, one kernel ----------------
__global__ void prep_kernel(const float* __restrict__ s0, u16* __restrict__ d0,   // 1048576 in_proj
                            const float* __restrict__ s1, u16* __restrict__ d1,   // 524288  out_proj
                            const float* __restrict__ s2, u16* __restrict__ d2,   // 1048576 ffn1
                            const float* __restrict__ s3, u16* __restrict__ d3,   // 1048576 ffn2
                            const float* __restrict__ s4, u16* __restrict__ d4,   // 65536   x_proj
                            const float* __restrict__ s5, u16* __restrict__ d5,   // 32768   dt_proj
                            const float* __restrict__ x, const float* __restrict__ g,
                            const float* __restrict__ b, u16* __restrict__ lnb)
{
    __shared__ float shs[4], shq[4];
    __shared__ float smu, srs;
    if (blockIdx.x < NCVT) {
        int i = (blockIdx.x * 256 + threadIdx.x) * 4;
        const float* sp; u16* dp; int off;
        if      (i < 1048576) { sp = s0; dp = d0; off = i; }
        else if (i < 1572864) { sp = s1; dp = d1; off = i - 1048576; }
        else if (i < 2621440) { sp = s2; dp = d2; off = i - 1572864; }
        else if (i < 3670016) { sp = s3; dp = d3; off = i - 2621440; }
        else if (i < 3735552) { sp = s4; dp = d4; off = i - 3670016; }
        else                  { sp = s5; dp = d5; off = i - 3735552; }
        float4 v = *(const float4*)(sp + off);
        ushort4 o;
        o.x = f2bf(v.x); o.y = f2bf(v.y); o.z = f2bf(v.z); o.w = f2bf(v.w);
        *(ushort4*)(dp + off) = o;
        return;
    }
    // LayerNorm branch: token t
    int t = blockIdx.x - NCVT;
    int tid = threadIdx.x;
    const float* xr = x + (size_t)t * DM;
    float v0 = xr[tid];
    float v1 = xr[tid + 256];
    float rsum = v0 + v1;
    float rsq  = v0 * v0 + v1 * v1;
    #pragma unroll
    for (int o = 32; o > 0; o >>= 1) { rsum += __shfl_down(rsum, o); rsq += __shfl_down(rsq, o); }
    int wid = tid >> 6, lane = tid & 63;
    if (lane == 0) { shs[wid] = rsum; shq[wid] = rsq; }
    __syncthreads();
    if (tid == 0) {
        float a  = shs[0] + shs[1] + shs[2] + shs[3];
        float a2 = shq[0] + shq[1] + shq[2] + shq[3];
        float mu = a / DM;
        float var = a2 / DM - mu * mu;
        smu = mu;
        srs = rsqrtf(var + 1e-5f);
    }
    __syncthreads();
    float mu = smu, rs = srs;
    u16* orow = lnb + (size_t)t * DM;
    orow[tid]       = f2bf((v0 - mu) * rs * g[tid]       + b[tid]);
    orow[tid + 256] = f2bf((v1 - mu) * rs * g[tid + 256] + b[tid + 256]);
}

// ---------------- standalone LayerNorm (LN2) ----------------
__global__ void ln_bf16_kernel(const float* __restrict__ x, const float* __restrict__ g,
                               const float* __restrict__ b, u16* __restrict__ out)
{
    int t = blockIdx.x;
    int tid = threadIdx.x;
    const float* xr = x + (size_t)t * DM;
    float v0 = xr[tid];
    float v1 = xr[tid + 256];
    float rsum = v0 + v1;
    float rsq  = v0 * v0 + v1 * v1;
    #pragma unroll
    for (int o = 32; o > 0; o >>= 1) { rsum += __shfl_down(rsum, o); rsq += __shfl_down(rsq, o); }
    __shared__ float shs[4], shq[4];
    __shared__ float smu, srs;
    int wid = tid >> 6, lane = tid & 63;
    if (lane == 0) { shs[wid] = rsum; shq[wid] = rsq; }
    __syncthreads();
    if (tid == 0) {
        float a  = shs[0] + shs[1] + shs[2] + shs[3];
        float a2 = shq[0] + shq[1] + shq[2] + shq[3];
        float mu = a / DM;
        float var = a2 / DM - mu * mu;
        smu = mu;
        srs = rsqrtf(var + 1e-5f);
    }
    __syncthreads();
    float mu = smu, rs = srs;
    u16* orow = out + (size_t)t * DM;
    orow[tid]       = f2bf((v0 - mu) * rs * g[tid]       + b[tid]);
    orow[tid + 256] = f2bf((v1 - mu) * rs * g[tid + 256] + b[tid + 256]);
}

// ---------------- 4-wave MFMA GEMM (generic BMxBN tiles, 2x2 wave grid) ----------------
// EPI: 0 plain, 2 bias+gelu, 3 +resid, 4 bias+resid. OBF: bf16 out.
template<int EPI, int BM, int BN, int BK, int OBF>
__global__ __launch_bounds__(256)
void mgemm_kernel(const u16* __restrict__ A, const u16* __restrict__ W, int K,
                  void* __restrict__ Cp, int ldc,
                  const float* __restrict__ bias, const float* __restrict__ resid, int ldr)
{
    __shared__ u16 As[BM * BK];
    __shared__ u16 Bs[BN * BK];
    constexpr int WR = BM / 2, WC = BN / 2;
    constexpr int MR = WR / 16, NR = WC / 16;
    constexpr int LPR = BK / 8;
    constexpr int CH_ROWS = 64 / LPR;
    constexpr int NCH_A = BM / CH_ROWS, NCH_B = BN / CH_ROWS;

    const int tid = threadIdx.x;
    const int wave = tid >> 6, lane = tid & 63;
    const int wm = wave >> 1, wn = wave & 1;
    const int m0 = blockIdx.y * BM, n0 = blockIdx.x * BN;
    const int crow = lane / LPR, ckoff = (lane % LPR) * 8;
    const int fr = lane & 15;

    f32x4 acc[MR][NR] = {};

    for (int k0 = 0; k0 < K; k0 += BK) {
        for (int c = wave; c < NCH_A; c += 4)
            async_cp16(A + (size_t)(m0 + c * CH_ROWS + crow) * K + k0 + ckoff, &As[c * 512]);
        for (int c = wave; c < NCH_B; c += 4)
            async_cp16(W + (size_t)(n0 + c * CH_ROWS + crow) * K + k0 + ckoff, &Bs[c * 512]);
        __syncthreads();
        #pragma unroll
        for (int ks = 0; ks < BK / 32; ++ks) {
            const int fk = ks * 32 + ((lane >> 4) << 3);
            bf16x8 af[MR], bv[NR];
            #pragma unroll
            for (int i = 0; i < MR; ++i)
                af[i] = *(const bf16x8*)&As[(wm * WR + i * 16 + fr) * BK + fk];
            #pragma unroll
            for (int j = 0; j < NR; ++j)
                bv[j] = *(const bf16x8*)&Bs[(wn * WC + j * 16 + fr) * BK + fk];
            #pragma unroll
            for (int i = 0; i < MR; ++i)
                #pragma unroll
                for (int j = 0; j < NR; ++j)
                    acc[i][j] = __builtin_amdgcn_mfma_f32_16x16x32_bf16(af[i], bv[j], acc[i][j], 0, 0, 0);
        }
        __syncthreads();
    }

    const int rbase = (lane >> 4) << 2;
    #pragma unroll
    for (int i = 0; i < MR; ++i) {
        #pragma unroll
        for (int j = 0; j < NR; ++j) {
            const int col  = n0 + wn * WC + j * 16 + fr;
            const int row0 = m0 + wm * WR + i * 16 + rbase;
            float bvv = (EPI == 2 || EPI == 4) ? bias[col] : 0.0f;
            #pragma unroll
            for (int r = 0; r < 4; ++r) {
                float v = acc[i][j][r];
                if (EPI == 2) v = geluf(v + bvv);
                if (EPI == 3) v += resid[(size_t)(row0 + r) * ldr + col];
                if (EPI == 4) v += bvv + resid[(size_t)(row0 + r) * ldr + col];
                if (OBF) ((u16*)Cp)[(size_t)(row0 + r) * ldc + col] = f2bf(v);
                else     ((float*)Cp)[(size_t)(row0 + r) * ldc + col] = v;
            }
        }
    }
}

// ---------------- x_proj split-K MFMA: P[ks][2048][64] partials ----------------
__global__ __launch_bounds__(256)
void xproj_part_kernel(const u16* __restrict__ A, const u16* __restrict__ W,
                       float* __restrict__ P)
{
    constexpr int BM = 64, BK = 128;
    __shared__ u16 As[BM * BK];
    __shared__ u16 Bs[64 * BK];
    const int tid = threadIdx.x;
    const int wave = tid >> 6, lane = tid & 63;
    const int wm = wave >> 1, wn = wave & 1;
    const int ks = blockIdx.x;               // 0..7
    const int m0 = blockIdx.y * BM;
    const int k0 = ks * BK;
    const int crow = lane >> 4, ckoff = (lane & 15) * 8;
    const int fr = lane & 15;

    for (int c = wave; c < 16; c += 4) {
        async_cp16(A + (size_t)(m0 + c * 4 + crow) * 1024 + k0 + ckoff, &As[c * 512]);
        async_cp16(W + (size_t)(c * 4 + crow) * 1024 + k0 + ckoff, &Bs[c * 512]);
    }
    __syncthreads();

    f32x4 acc[2][2] = {};
    #pragma unroll
    for (int ks2 = 0; ks2 < 4; ++ks2) {
        const int fk = ks2 * 32 + ((lane >> 4) << 3);
        bf16x8 af[2], bv[2];
        #pragma unroll
        for (int i = 0; i < 2; ++i)
            af[i] = *(const bf16x8*)&As[(wm * 32 + i * 16 + fr) * BK + fk];
        #pragma unroll
        for (int j = 0; j < 2; ++j)
            bv[j] = *(const bf16x8*)&Bs[(wn * 32 + j * 16 + fr) * BK + fk];
        #pragma unroll
        for (int i = 0; i < 2; ++i)
            #pragma unroll
            for (int j = 0; j < 2; ++j)
                acc[i][j] = __builtin_amdgcn_mfma_f32_16x16x32_bf16(af[i], bv[j], acc[i][j], 0, 0, 0);
    }

    const int rbase = (lane >> 4) << 2;
    float* Pk = P + (size_t)ks * NTOK * 64;
    #pragma unroll
    for (int i = 0; i < 2; ++i)
        #pragma unroll
        for (int j = 0; j < 2; ++j) {
            const int col  = wn * 32 + j * 16 + fr;
            const int row0 = m0 + wm * 32 + i * 16 + rbase;
            #pragma unroll
            for (int r = 0; r < 4; ++r)
                Pk[(size_t)(row0 + r) * 64 + col] = acc[i][j][r];
        }
}

// reduce partials -> xdbl fp32 [2048,64]; also emit dt columns (0..31) as bf16 [2048,32]
__global__ void xproj_reduce_kernel(const float* __restrict__ P, float* __restrict__ xdbl,
                                    u16* __restrict__ dtb)
{
    int i = blockIdx.x * 256 + threadIdx.x;   // over 2048*64
    float s = 0.0f;
    #pragma unroll
    for (int ks = 0; ks < 8; ++ks) s += P[(size_t)ks * NTOK * 64 + i];
    xdbl[i] = s;
    int col = i & 63;
    if (col < 32) dtb[(i >> 6) * 32 + col] = f2bf(s);
}

// ---------------- depthwise causal conv1d (width 4) + SiLU; bf16 in/out, 8 ch/thread ----------------
__global__ void conv_silu_kernel(const u16* __restrict__ xz,
                                 const float* __restrict__ cw,
                                 const float* __restrict__ cb,
                                 u16* __restrict__ xcb)
{
    int idx = blockIdx.x * 256 + threadIdx.x;   // over NTOK*DI/8
    int e8 = idx & (DI / 8 - 1);
    int e  = e8 * 8;
    int t  = idx >> 7;
    int l  = t & (LSEQ - 1);
    const u16* base = xz + (size_t)t * 2048 + e;
    bf16x8 r0 = {}, r1 = {}, r2 = {}, r3;
    r3 = *(const bf16x8*)(base);
    if (l >= 1) r2 = *(const bf16x8*)(base - 2048);
    if (l >= 2) r1 = *(const bf16x8*)(base - 2 * 2048);
    if (l >= 3) r0 = *(const bf16x8*)(base - 3 * 2048);
    float o[8];
    #pragma unroll
    for (int j = 0; j < 8; ++j) {
        const float4 w = *(const float4*)(cw + (e + j) * 4);
        float acc = cb[e + j];
        acc = fmaf(bf2f((u16)r0[j]), w.x, acc);
        acc = fmaf(bf2f((u16)r1[j]), w.y, acc);
        acc = fmaf(bf2f((u16)r2[j]), w.z, acc);
        acc = fmaf(bf2f((u16)r3[j]), w.w, acc);
        o[j] = siluf(acc);
    }
    bf16x8 obf;
    #pragma unroll
    for (int j = 0; j < 8; ++j) obf[j] = (short)f2bf(o[j]);
    *(bf16x8*)(xcb + (size_t)t * DI + e) = obf;
}

// ---- inline dt_proj + softplus: delta for one (tok, e). dtb row is wave-uniform ----
__device__ __forceinline__ float delta_of(const u16* __restrict__ dtb, size_t tok,
                                          const bf16x8* wv, float dbias)
{
    float dt = dbias;
    const u16* dr = dtb + tok * 32;
    #pragma unroll
    for (int q = 0; q < 4; ++q) {
        bf16x8 dv = *(const bf16x8*)(dr + q * 8);
        #pragma unroll
        for (int k = 0; k < 8; ++k)
            dt = fmaf(bf2f((u16)dv[k]), bf2f((u16)wv[q][k]), dt);
    }
    return (dt < 20.0f) ? log1pf(__expf(dt)) : dt;
}

// ============ chunked selective scan (NC=64, CL=16); dt_proj inlined ============
// Layouts (e innermost => all accesses wave-coalesced):
//   qbuf[((b*NC+c)*16+n)*DI + e]  bf16
//   hin [((b*NC+c)*16+n)*DI + e]  bf16
//   sumd[(b*NC+c)*DI + e]         fp32
__global__ void scanA_kernel(const u16* __restrict__ dtb,
                             const u16* __restrict__ wdt,
                             const float* __restrict__ dt_bias,
                             const u16* __restrict__ xcb,
                             const float* __restrict__ xdbl,
                             const float* __restrict__ A_log,
                             u16* __restrict__ qbuf,
                             float* __restrict__ sumd)
{
    int i = blockIdx.x * 256 + threadIdx.x;   // ((b*NC + c) << 10) | e
    int e = i & (DI - 1);
    int bc = i >> 10;                          // b*NC + c
    int c = bc & (NC - 1);
    int b = bc >> 6;
    float Ae[16], h[16];
    #pragma unroll
    for (int n = 0; n < 16; ++n) { Ae[n] = -__expf(A_log[e * 16 + n]); h[n] = 0.0f; }
    const float dbias = dt_bias[e];
    bf16x8 wv[4];
    #pragma unroll
    for (int q = 0; q < 4; ++q) wv[q] = *(const bf16x8*)(wdt + e * 32 + q * 8);
    float sd = 0.0f;
    int l0 = c * CL;
    for (int l = 0; l < CL; ++l) {
        size_t tok = (size_t)b * LSEQ + l0 + l;
        float d = delta_of(dtb, tok, wv, dbias);
        float xcv = bf2f(xcb[tok * DI + e]);
        sd += d;
        float dx = d * xcv;
        const float4* B4 = (const float4*)(xdbl + tok * 64 + 32);
        #pragma unroll
        for (int q = 0; q < 4; ++q) {
            float4 Bq = B4[q];
            h[4*q+0] = __expf(d * Ae[4*q+0]) * h[4*q+0] + dx * Bq.x;
            h[4*q+1] = __expf(d * Ae[4*q+1]) * h[4*q+1] + dx * Bq.y;
            h[4*q+2] = __expf(d * Ae[4*q+2]) * h[4*q+2] + dx * Bq.z;
            h[4*q+3] = __expf(d * Ae[4*q+3]) * h[4*q+3] + dx * Bq.w;
        }
    }
    size_t qbase = (size_t)bc * 16 * DI + e;
    #pragma unroll
    for (int n = 0; n < 16; ++n) qbuf[qbase + (size_t)n * DI] = f2bf(h[n]);
    sumd[(size_t)bc * DI + e] = sd;
}

__global__ void scanB_kernel(const u16* __restrict__ qbuf,
                             const float* __restrict__ sumd,
                             const float* __restrict__ A_log,
                             u16* __restrict__ hin)
{
    int i = blockIdx.x * 256 + threadIdx.x;   // ((b*16 + n) << 10) | e
    int e = i & (DI - 1);
    int bn = i >> 10;
    int n = bn & 15;
    int b = bn >> 4;
    float Ae = -__expf(A_log[e * 16 + n]);
    float h = 0.0f;
    for (int c = 0; c < NC; ++c) {
        size_t idx = ((size_t)((b * NC + c) * 16 + n)) * DI + e;
        hin[idx] = f2bf(h);
        float P = __expf(Ae * sumd[(size_t)(b * NC + c) * DI + e]);
        h = P * h + bf2f(qbuf[idx]);
    }
}

// Pass C: replay from entry state; y (bf16) = (scan + xc*D) * silu(z)
__global__ void scanC_kernel(const u16* __restrict__ dtb,
                             const u16* __restrict__ wdt,
                             const float* __restrict__ dt_bias,
                             const u16* __restrict__ xcb,
                             const float* __restrict__ xdbl,
                             const u16* __restrict__ xz,
                             const float* __restrict__ A_log,
                             const float* __restrict__ Dp,
                             const u16* __restrict__ hin,
                             u16* __restrict__ y)
{
    int i = blockIdx.x * 256 + threadIdx.x;
    int e = i & (DI - 1);
    int bc = i >> 10;
    int c = bc & (NC - 1);
    int b = bc >> 6;
    float Ae[16], h[16];
    size_t hbase = (size_t)bc * 16 * DI + e;
    #pragma unroll
    for (int n = 0; n < 16; ++n) {
        Ae[n] = -__expf(A_log[e * 16 + n]);
        h[n] = bf2f(hin[hbase + (size_t)n * DI]);
    }
    const float dbias = dt_bias[e];
    bf16x8 wv[4];
    #pragma unroll
    for (int q = 0; q < 4; ++q) wv[q] = *(const bf16x8*)(wdt + e * 32 + q * 8);
    float Dv = Dp[e];
    int l0 = c * CL;
    for (int l = 0; l < CL; ++l) {
        size_t tok = (size_t)b * LSEQ + l0 + l;
        float d = delta_of(dtb, tok, wv, dbias);
        float xcv = bf2f(xcb[tok * DI + e]);
        float zv  = bf2f(xz[tok * 2048 + DI + e]);
        float dx = d * xcv;
        const float4* B4 = (const float4*)(xdbl + tok * 64 + 32);
        const float4* C4 = (const float4*)(xdbl + tok * 64 + 48);
        float yv = 0.0f;
        #pragma unroll
        for (int q = 0; q < 4; ++q) {
            float4 Bq = B4[q];
            float4 Cq = C4[q];
            float hb;
            hb = __expf(d * Ae[4*q+0]) * h[4*q+0] + dx * Bq.x; h[4*q+0] = hb; yv = fmaf(hb, Cq.x, yv);
            hb = __expf(d * Ae[4*q+1]) * h[4*q+1] + dx * Bq.y; h[4*q+1] = hb; yv = fmaf(hb, Cq.y, yv);
            hb = __expf(d * Ae[4*q+2]) * h[4*q+2] + dx * Bq.z; h[4*q+2] = hb; yv = fmaf(hb, Cq.z, yv);
            hb = __expf(d * Ae[4*q+3]) * h[4*q+3] + dx * Bq.w; h[4*q+3] = hb; yv = fmaf(hb, Cq.w, yv);
        }
        yv += xcv * Dv;
        yv *= siluf(zv);
        y[tok * DI + e] = f2bf(yv);
    }
}

extern "C" void kernel_launch(void* const* d_in, const int* in_sizes, int n_in,
                              void* d_out, int out_size, void* d_ws, size_t ws_size,
                              hipStream_t stream)
{
    const float* x         = (const float*)d_in[0];
    const float* ln1_g     = (const float*)d_in[1];
    const float* ln1_b     = (const float*)d_in[2];
    const float* in_proj_w = (const float*)d_in[3];
    const float* conv_w    = (const float*)d_in[4];
    const float* conv_b    = (const float*)d_in[5];
    const float* x_proj_w  = (const float*)d_in[6];
    const float* dt_proj_w = (const float*)d_in[7];
    const float* dt_proj_b = (const float*)d_in[8];
    const float* A_log     = (const float*)d_in[9];
    const float* Dp        = (const float*)d_in[10];
    const float* out_proj_w= (const float*)d_in[11];
    const float* ln2_g     = (const float*)d_in[12];
    const float* ln2_b     = (const float*)d_in[13];
    const float* ffn1_w    = (const float*)d_in[14];
    const float* ffn1_b    = (const float*)d_in[15];
    const float* ffn2_w    = (const float*)d_in[16];
    const float* ffn2_b    = (const float*)d_in[17];
    float* out = (float*)d_out;

    // -------- workspace carve, no aliasing --------
    char* wsb = (char*)d_ws;
    u16*   lnb   = (u16*)wsb;    wsb += (size_t)2048 * 512 * 2;       // 2MB
    u16*   xzb   = (u16*)wsb;    wsb += (size_t)2048 * 2048 * 2;      // 8MB
    u16*   xcb   = (u16*)wsb;    wsb += (size_t)2048 * 1024 * 2;      // 4MB
    float* xdbl  = (float*)wsb;  wsb += (size_t)2048 * 64 * 4;        // 512KB
    u16*   dtb   = (u16*)wsb;    wsb += (size_t)2048 * 32 * 2;        // 128KB
    float* Ppart = (float*)wsb;  wsb += (size_t)8 * 2048 * 64 * 4;    // 4MB
    u16*   qbuf  = (u16*)wsb;    wsb += (size_t)BB * NC * 16 * DI * 2;// 4MB
    float* sumd  = (float*)wsb;  wsb += (size_t)BB * NC * DI * 4;     // 512KB
    u16*   hin   = (u16*)wsb;    wsb += (size_t)BB * NC * 16 * DI * 2;// 4MB
    u16*   ybuf  = (u16*)wsb;    wsb += (size_t)2048 * 1024 * 2;      // 4MB
    float* x2    = (float*)wsb;  wsb += (size_t)2048 * 512 * 4;       // 4MB
    u16*   ffnm  = (u16*)wsb;    wsb += (size_t)2048 * 2048 * 2;      // 8MB
    u16*   w_in  = (u16*)wsb;    wsb += (size_t)2048 * 512 * 2;       // 2MB
    u16*   w_out = (u16*)wsb;    wsb += (size_t)512 * 1024 * 2;       // 1MB
    u16*   w_f1  = (u16*)wsb;    wsb += (size_t)2048 * 512 * 2;       // 2MB
    u16*   w_f2  = (u16*)wsb;    wsb += (size_t)512 * 2048 * 2;       // 2MB
    u16*   w_x   = (u16*)wsb;    wsb += (size_t)64 * 1024 * 2;        // 128KB
    u16*   w_dt  = (u16*)wsb;    wsb += (size_t)1024 * 32 * 2;        // 64KB

    // 0+1) weight conversions + LN1 (fused)
    prep_kernel<<<NCVT + NTOK, 256, 0, stream>>>(in_proj_w, w_in, out_proj_w, w_out,
                                                 ffn1_w, w_f1, ffn2_w, w_f2,
                                                 x_proj_w, w_x, dt_proj_w, w_dt,
                                                 x, ln1_g, ln1_b, lnb);
    // 2) in_proj MFMA 128x64 tile, 512 blocks (2 blocks/CU): -> xz bf16 [2048,2048]
    mgemm_kernel<0,128,64,64,1><<<dim3(32,16), 256, 0, stream>>>(lnb, w_in, 512, xzb, 2048, nullptr, nullptr, 0);
    // 3) conv + silu -> xcb bf16
    conv_silu_kernel<<<(NTOK * DI) / (256 * 8), 256, 0, stream>>>(xzb, conv_w, conv_b, xcb);
    // 4) x_proj split-K MFMA + reduce -> xdbl fp32 + dtb bf16
    xproj_part_kernel<<<dim3(8, 32), 256, 0, stream>>>(xcb, w_x, Ppart);
    xproj_reduce_kernel<<<(NTOK * 64) / 256, 256, 0, stream>>>(Ppart, xdbl, dtb);
    // 5) chunked scan, dt_proj inlined (NC=64, CL=16), bf16 e-innermost intermediates
    scanA_kernel<<<(BB * NC * DI) / 256, 256, 0, stream>>>(dtb, w_dt, dt_proj_b, xcb, xdbl, A_log, qbuf, sumd);
    scanB_kernel<<<(BB * 16 * DI) / 256, 256, 0, stream>>>(qbuf, sumd, A_log, hin);
    scanC_kernel<<<(BB * NC * DI) / 256, 256, 0, stream>>>(dtb, w_dt, dt_proj_b, xcb, xdbl, xzb, A_log, Dp, hin, ybuf);
    // 6) out_proj MFMA + residual(x): [2048,1024]x[512,1024]^T -> x2 fp32
    mgemm_kernel<3,64,64,128,0><<<dim3(8,32), 256, 0, stream>>>(ybuf, w_out, 1024, x2, 512, nullptr, x, 512);
    // 7) LN2 -> bf16
    ln_bf16_kernel<<<NTOK, 256, 0, stream>>>(x2, ln2_g, ln2_b, lnb);
    // 8) ffn1 MFMA 128x64 tile + bias + gelu -> ffn_mid bf16 [2048,2048]
    mgemm_kernel<2,128,64,64,1><<<dim3(32,16), 256, 0, stream>>>(lnb, w_f1, 512, ffnm, 2048, ffn1_b, nullptr, 0);
    // 9) ffn2 MFMA + bias + residual(x2) -> out fp32
    mgemm_kernel<4,64,64,128,0><<<dim3(8,32), 256, 0, stream>>>(ffnm, w_f2, 2048, out, 512, ffn2_b, x2, 512);
}

// Round 12
// 169.103 us; speedup vs baseline: 1.3548x; 1.0124x over previous
//
#include <hip/hip_runtime.h>
#include <cmath>

typedef unsigned short u16;
typedef __attribute__((ext_vector_type(8))) short bf16x8;
typedef __attribute__((ext_vector_type(4))) float f32x4;

#define BB    2
#define LSEQ  1024
#define DM    512
#define DI    1024
#define NTOK  2048   // BB*LSEQ
#define NC    64     // chunks per sequence
#define CL    16     // chunk length

__device__ __forceinline__ float siluf(float x) {
    return x * (1.0f / (1.0f + __expf(-x)));
}
__device__ __forceinline__ float geluf(float x) {
    float c = 0.7978845608028654f * (x + 0.044715f * x * x * x);
    return 0.5f * x * (1.0f + tanhf(c));
}
__device__ __forceinline__ u16 f2bf(float f) {
    union { float f; unsigned u; } v; v.f = f;
    unsigned r = v.u + 0x7fff + ((v.u >> 16) & 1);
    return (u16)(r >> 16);
}
__device__ __forceinline__ float bf2f(u16 u) {
    union { unsigned u; float f; } v; v.u = ((unsigned)u) << 16; return v.f;
}
__device__ __forceinline__ void async_cp16(const u16* g, u16* l) {
    __builtin_amdgcn_global_load_lds(
        (const __attribute__((address_space(1))) void*)g,
        (__attribute__((address_space(3))) void*)l, 16, 0, 0);
}

#define NCVT 3680   // blocks for weight conversion (3768320 elems / 1024)

// ---------------- prep: weight bf16 conversion + LN1, one kernel ----------------
__global__ void prep_kernel(const float* __restrict__ s0, u16* __restrict__ d0,   // 1048576 in_proj
                            const float* __restrict__ s1, u16* __restrict__ d1,   // 524288  out_proj
                            const float* __restrict__ s2, u16* __restrict__ d2,   // 1048576 ffn1
                            const float* __restrict__ s3, u16* __restrict__ d3,   // 1048576 ffn2
                            const float* __restrict__ s4, u16* __restrict__ d4,   // 65536   x_proj
                            const float* __restrict__ s5, u16* __restrict__ d5,   // 32768   dt_proj
                            const float* __restrict__ x, const float* __restrict__ g,
                            const float* __restrict__ b, u16* __restrict__ lnb)
{
    __shared__ float shs[4], shq[4];
    __shared__ float smu, srs;
    if (blockIdx.x < NCVT) {
        int i = (blockIdx.x * 256 + threadIdx.x) * 4;
        const float* sp; u16* dp; int off;
        if      (i < 1048576) { sp = s0; dp = d0; off = i; }
        else if (i < 1572864) { sp = s1; dp = d1; off = i - 1048576; }
        else if (i < 2621440) { sp = s2; dp = d2; off = i - 1572864; }
        else if (i < 3670016) { sp = s3; dp = d3; off = i - 2621440; }
        else if (i < 3735552) { sp = s4; dp = d4; off = i - 3670016; }
        else                  { sp = s5; dp = d5; off = i - 3735552; }
        float4 v = *(const float4*)(sp + off);
        ushort4 o;
        o.x = f2bf(v.x); o.y = f2bf(v.y); o.z = f2bf(v.z); o.w = f2bf(v.w);
        *(ushort4*)(dp + off) = o;
        return;
    }
    // LayerNorm branch: token t
    int t = blockIdx.x - NCVT;
    int tid = threadIdx.x;
    const float* xr = x + (size_t)t * DM;
    float v0 = xr[tid];
    float v1 = xr[tid + 256];
    float rsum = v0 + v1;
    float rsq  = v0 * v0 + v1 * v1;
    #pragma unroll
    for (int o = 32; o > 0; o >>= 1) { rsum += __shfl_down(rsum, o); rsq += __shfl_down(rsq, o); }
    int wid = tid >> 6, lane = tid & 63;
    if (lane == 0) { shs[wid] = rsum; shq[wid] = rsq; }
    __syncthreads();
    if (tid == 0) {
        float a  = shs[0] + shs[1] + shs[2] + shs[3];
        float a2 = shq[0] + shq[1] + shq[2] + shq[3];
        float mu = a / DM;
        float var = a2 / DM - mu * mu;
        smu = mu;
        srs = rsqrtf(var + 1e-5f);
    }
    __syncthreads();
    float mu = smu, rs = srs;
    u16* orow = lnb + (size_t)t * DM;
    orow[tid]       = f2bf((v0 - mu) * rs * g[tid]       + b[tid]);
    orow[tid + 256] = f2bf((v1 - mu) * rs * g[tid + 256] + b[tid + 256]);
}

// ---------------- standalone LayerNorm (LN2) ----------------
__global__ void ln_bf16_kernel(const float* __restrict__ x, const float* __restrict__ g,
                               const float* __restrict__ b, u16* __restrict__ out)
{
    int t = blockIdx.x;
    int tid = threadIdx.x;
    const float* xr = x + (size_t)t * DM;
    float v0 = xr[tid];
    float v1 = xr[tid + 256];
    float rsum = v0 + v1;
    float rsq  = v0 * v0 + v1 * v1;
    #pragma unroll
    for (int o = 32; o > 0; o >>= 1) { rsum += __shfl_down(rsum, o); rsq += __shfl_down(rsq, o); }
    __shared__ float shs[4], shq[4];
    __shared__ float smu, srs;
    int wid = tid >> 6, lane = tid & 63;
    if (lane == 0) { shs[wid] = rsum; shq[wid] = rsq; }
    __syncthreads();
    if (tid == 0) {
        float a  = shs[0] + shs[1] + shs[2] + shs[3];
        float a2 = shq[0] + shq[1] + shq[2] + shq[3];
        float mu = a / DM;
        float var = a2 / DM - mu * mu;
        smu = mu;
        srs = rsqrtf(var + 1e-5f);
    }
    __syncthreads();
    float mu = smu, rs = srs;
    u16* orow = out + (size_t)t * DM;
    orow[tid]       = f2bf((v0 - mu) * rs * g[tid]       + b[tid]);
    orow[tid + 256] = f2bf((v1 - mu) * rs * g[tid + 256] + b[tid + 256]);
}

// ---------------- 4-wave MFMA GEMM (generic BMxBN tiles, 2x2 wave grid) ----------------
// EPI: 0 plain, 2 bias+gelu, 3 +resid, 4 bias+resid. OBF: bf16 out.
template<int EPI, int BM, int BN, int BK, int OBF>
__global__ __launch_bounds__(256)
void mgemm_kernel(const u16* __restrict__ A, const u16* __restrict__ W, int K,
                  void* __restrict__ Cp, int ldc,
                  const float* __restrict__ bias, const float* __restrict__ resid, int ldr)
{
    __shared__ u16 As[BM * BK];
    __shared__ u16 Bs[BN * BK];
    constexpr int WR = BM / 2, WC = BN / 2;
    constexpr int MR = WR / 16, NR = WC / 16;
    constexpr int LPR = BK / 8;
    constexpr int CH_ROWS = 64 / LPR;
    constexpr int NCH_A = BM / CH_ROWS, NCH_B = BN / CH_ROWS;

    const int tid = threadIdx.x;
    const int wave = tid >> 6, lane = tid & 63;
    const int wm = wave >> 1, wn = wave & 1;
    const int m0 = blockIdx.y * BM, n0 = blockIdx.x * BN;
    const int crow = lane / LPR, ckoff = (lane % LPR) * 8;
    const int fr = lane & 15;

    f32x4 acc[MR][NR] = {};

    for (int k0 = 0; k0 < K; k0 += BK) {
        for (int c = wave; c < NCH_A; c += 4)
            async_cp16(A + (size_t)(m0 + c * CH_ROWS + crow) * K + k0 + ckoff, &As[c * 512]);
        for (int c = wave; c < NCH_B; c += 4)
            async_cp16(W + (size_t)(n0 + c * CH_ROWS + crow) * K + k0 + ckoff, &Bs[c * 512]);
        __syncthreads();
        #pragma unroll
        for (int ks = 0; ks < BK / 32; ++ks) {
            const int fk = ks * 32 + ((lane >> 4) << 3);
            bf16x8 af[MR], bv[NR];
            #pragma unroll
            for (int i = 0; i < MR; ++i)
                af[i] = *(const bf16x8*)&As[(wm * WR + i * 16 + fr) * BK + fk];
            #pragma unroll
            for (int j = 0; j < NR; ++j)
                bv[j] = *(const bf16x8*)&Bs[(wn * WC + j * 16 + fr) * BK + fk];
            #pragma unroll
            for (int i = 0; i < MR; ++i)
                #pragma unroll
                for (int j = 0; j < NR; ++j)
                    acc[i][j] = __builtin_amdgcn_mfma_f32_16x16x32_bf16(af[i], bv[j], acc[i][j], 0, 0, 0);
        }
        __syncthreads();
    }

    const int rbase = (lane >> 4) << 2;
    #pragma unroll
    for (int i = 0; i < MR; ++i) {
        #pragma unroll
        for (int j = 0; j < NR; ++j) {
            const int col  = n0 + wn * WC + j * 16 + fr;
            const int row0 = m0 + wm * WR + i * 16 + rbase;
            float bvv = (EPI == 2 || EPI == 4) ? bias[col] : 0.0f;
            #pragma unroll
            for (int r = 0; r < 4; ++r) {
                float v = acc[i][j][r];
                if (EPI == 2) v = geluf(v + bvv);
                if (EPI == 3) v += resid[(size_t)(row0 + r) * ldr + col];
                if (EPI == 4) v += bvv + resid[(size_t)(row0 + r) * ldr + col];
                if (OBF) ((u16*)Cp)[(size_t)(row0 + r) * ldc + col] = f2bf(v);
                else     ((float*)Cp)[(size_t)(row0 + r) * ldc + col] = v;
            }
        }
    }
}

// ---------------- FUSED conv+SiLU + x_proj split-K MFMA ----------------
// Block (ks, mb): computes conv+silu for tokens m0..m0+63, channels k0..k0+127
// directly into its LDS A-tile (and to xcb global for the scans), then does the
// 64x64x128 MFMA against x_proj weights. P[ks][2048][64] partials out.
__global__ __launch_bounds__(256)
void xproj_conv_kernel(const u16* __restrict__ xz,      // [NTOK,2048] bf16
                       const float* __restrict__ cw, const float* __restrict__ cb,
                       const u16* __restrict__ wx,      // [64,1024] bf16
                       u16* __restrict__ xcb,           // [NTOK,DI] bf16 out
                       float* __restrict__ P)
{
    constexpr int BM = 64, BK = 128;
    __shared__ u16 As[BM * BK];
    __shared__ u16 Bs[64 * BK];
    const int tid = threadIdx.x;
    const int wave = tid >> 6, lane = tid & 63;
    const int wm = wave >> 1, wn = wave & 1;
    const int ks = blockIdx.x;               // 0..7
    const int m0 = blockIdx.y * BM;
    const int k0 = ks * BK;
    const int fr = lane & 15;

    // stage B (x_proj weights) via global_load_lds
    {
        const int crow = lane >> 4, ckoff = (lane & 15) * 8;
        for (int c = wave; c < 16; c += 4)
            async_cp16(wx + (size_t)(c * 4 + crow) * 1024 + k0 + ckoff, &Bs[c * 512]);
    }
    // conv + silu into A-tile (LDS) + xcb (global). 8 ch/thread, 4 iters.
    #pragma unroll
    for (int it = tid; it < BM * (BK / 8); it += 256) {
        const int row = it >> 4;             // 0..63 (token within tile)
        const int c8  = it & 15;             // 0..15 (channel-octet)
        const int e   = k0 + c8 * 8;
        const int t   = m0 + row;
        const int l   = t & (LSEQ - 1);
        const u16* base = xz + (size_t)t * 2048 + e;
        bf16x8 r0 = {}, r1 = {}, r2 = {}, r3;
        r3 = *(const bf16x8*)(base);
        if (l >= 1) r2 = *(const bf16x8*)(base - 2048);
        if (l >= 2) r1 = *(const bf16x8*)(base - 2 * 2048);
        if (l >= 3) r0 = *(const bf16x8*)(base - 3 * 2048);
        bf16x8 obf;
        #pragma unroll
        for (int j = 0; j < 8; ++j) {
            const float4 w = *(const float4*)(cw + (e + j) * 4);
            float acc = cb[e + j];
            acc = fmaf(bf2f((u16)r0[j]), w.x, acc);
            acc = fmaf(bf2f((u16)r1[j]), w.y, acc);
            acc = fmaf(bf2f((u16)r2[j]), w.z, acc);
            acc = fmaf(bf2f((u16)r3[j]), w.w, acc);
            obf[j] = (short)f2bf(siluf(acc));
        }
        *(bf16x8*)&As[row * BK + c8 * 8] = obf;
        *(bf16x8*)(xcb + (size_t)t * DI + e) = obf;
    }
    __syncthreads();   // drains lgkm (LDS writes) + vm (global_load_lds)

    f32x4 acc[2][2] = {};
    #pragma unroll
    for (int ks2 = 0; ks2 < 4; ++ks2) {
        const int fk = ks2 * 32 + ((lane >> 4) << 3);
        bf16x8 af[2], bv[2];
        #pragma unroll
        for (int i = 0; i < 2; ++i)
            af[i] = *(const bf16x8*)&As[(wm * 32 + i * 16 + fr) * BK + fk];
        #pragma unroll
        for (int j = 0; j < 2; ++j)
            bv[j] = *(const bf16x8*)&Bs[(wn * 32 + j * 16 + fr) * BK + fk];
        #pragma unroll
        for (int i = 0; i < 2; ++i)
            #pragma unroll
            for (int j = 0; j < 2; ++j)
                acc[i][j] = __builtin_amdgcn_mfma_f32_16x16x32_bf16(af[i], bv[j], acc[i][j], 0, 0, 0);
    }

    const int rbase = (lane >> 4) << 2;
    float* Pk = P + (size_t)ks * NTOK * 64;
    #pragma unroll
    for (int i = 0; i < 2; ++i)
        #pragma unroll
        for (int j = 0; j < 2; ++j) {
            const int col  = wn * 32 + j * 16 + fr;
            const int row0 = m0 + wm * 32 + i * 16 + rbase;
            #pragma unroll
            for (int r = 0; r < 4; ++r)
                Pk[(size_t)(row0 + r) * 64 + col] = acc[i][j][r];
        }
}

// reduce partials -> xdbl fp32 [2048,64]; also emit dt columns (0..31) as bf16 [2048,32]
__global__ void xproj_reduce_kernel(const float* __restrict__ P, float* __restrict__ xdbl,
                                    u16* __restrict__ dtb)
{
    int i = blockIdx.x * 256 + threadIdx.x;   // over 2048*64
    float s = 0.0f;
    #pragma unroll
    for (int ks = 0; ks < 8; ++ks) s += P[(size_t)ks * NTOK * 64 + i];
    xdbl[i] = s;
    int col = i & 63;
    if (col < 32) dtb[(i >> 6) * 32 + col] = f2bf(s);
}

// ---- inline dt_proj + softplus: delta for one (tok, e). dtb row is wave-uniform ----
__device__ __forceinline__ float delta_of(const u16* __restrict__ dtb, size_t tok,
                                          const bf16x8* wv, float dbias)
{
    float dt = dbias;
    const u16* dr = dtb + tok * 32;
    #pragma unroll
    for (int q = 0; q < 4; ++q) {
        bf16x8 dv = *(const bf16x8*)(dr + q * 8);
        #pragma unroll
        for (int k = 0; k < 8; ++k)
            dt = fmaf(bf2f((u16)dv[k]), bf2f((u16)wv[q][k]), dt);
    }
    return (dt < 20.0f) ? log1pf(__expf(dt)) : dt;
}

// ============ chunked selective scan (NC=64, CL=16); dt_proj inlined ============
// Layouts (e innermost => all accesses wave-coalesced):
//   qbuf[((b*NC+c)*16+n)*DI + e]  bf16
//   hin [((b*NC+c)*16+n)*DI + e]  bf16
//   sumd[(b*NC+c)*DI + e]         fp32
__global__ void scanA_kernel(const u16* __restrict__ dtb,
                             const u16* __restrict__ wdt,
                             const float* __restrict__ dt_bias,
                             const u16* __restrict__ xcb,
                             const float* __restrict__ xdbl,
                             const float* __restrict__ A_log,
                             u16* __restrict__ qbuf,
                             float* __restrict__ sumd)
{
    int i = blockIdx.x * 256 + threadIdx.x;   // ((b*NC + c) << 10) | e
    int e = i & (DI - 1);
    int bc = i >> 10;                          // b*NC + c
    int c = bc & (NC - 1);
    int b = bc >> 6;
    float Ae[16], h[16];
    #pragma unroll
    for (int n = 0; n < 16; ++n) { Ae[n] = -__expf(A_log[e * 16 + n]); h[n] = 0.0f; }
    const float dbias = dt_bias[e];
    bf16x8 wv[4];
    #pragma unroll
    for (int q = 0; q < 4; ++q) wv[q] = *(const bf16x8*)(wdt + e * 32 + q * 8);
    float sd = 0.0f;
    int l0 = c * CL;
    for (int l = 0; l < CL; ++l) {
        size_t tok = (size_t)b * LSEQ + l0 + l;
        float d = delta_of(dtb, tok, wv, dbias);
        float xcv = bf2f(xcb[tok * DI + e]);
        sd += d;
        float dx = d * xcv;
        const float4* B4 = (const float4*)(xdbl + tok * 64 + 32);
        #pragma unroll
        for (int q = 0; q < 4; ++q) {
            float4 Bq = B4[q];
            h[4*q+0] = __expf(d * Ae[4*q+0]) * h[4*q+0] + dx * Bq.x;
            h[4*q+1] = __expf(d * Ae[4*q+1]) * h[4*q+1] + dx * Bq.y;
            h[4*q+2] = __expf(d * Ae[4*q+2]) * h[4*q+2] + dx * Bq.z;
            h[4*q+3] = __expf(d * Ae[4*q+3]) * h[4*q+3] + dx * Bq.w;
        }
    }
    size_t qbase = (size_t)bc * 16 * DI + e;
    #pragma unroll
    for (int n = 0; n < 16; ++n) qbuf[qbase + (size_t)n * DI] = f2bf(h[n]);
    sumd[(size_t)bc * DI + e] = sd;
}

__global__ void scanB_kernel(const u16* __restrict__ qbuf,
                             const float* __restrict__ sumd,
                             const float* __restrict__ A_log,
                             u16* __restrict__ hin)
{
    int i = blockIdx.x * 256 + threadIdx.x;   // ((b*16 + n) << 10) | e
    int e = i & (DI - 1);
    int bn = i >> 10;
    int n = bn & 15;
    int b = bn >> 4;
    float Ae = -__expf(A_log[e * 16 + n]);
    float h = 0.0f;
    for (int c = 0; c < NC; ++c) {
        size_t idx = ((size_t)((b * NC + c) * 16 + n)) * DI + e;
        hin[idx] = f2bf(h);
        float P = __expf(Ae * sumd[(size_t)(b * NC + c) * DI + e]);
        h = P * h + bf2f(qbuf[idx]);
    }
}

// Pass C: replay from entry state; y (bf16) = (scan + xc*D) * silu(z)
__global__ void scanC_kernel(const u16* __restrict__ dtb,
                             const u16* __restrict__ wdt,
                             const float* __restrict__ dt_bias,
                             const u16* __restrict__ xcb,
                             const float* __restrict__ xdbl,
                             const u16* __restrict__ xz,
                             const float* __restrict__ A_log,
                             const float* __restrict__ Dp,
                             const u16* __restrict__ hin,
                             u16* __restrict__ y)
{
    int i = blockIdx.x * 256 + threadIdx.x;
    int e = i & (DI - 1);
    int bc = i >> 10;
    int c = bc & (NC - 1);
    int b = bc >> 6;
    float Ae[16], h[16];
    size_t hbase = (size_t)bc * 16 * DI + e;
    #pragma unroll
    for (int n = 0; n < 16; ++n) {
        Ae[n] = -__expf(A_log[e * 16 + n]);
        h[n] = bf2f(hin[hbase + (size_t)n * DI]);
    }
    const float dbias = dt_bias[e];
    bf16x8 wv[4];
    #pragma unroll
    for (int q = 0; q < 4; ++q) wv[q] = *(const bf16x8*)(wdt + e * 32 + q * 8);
    float Dv = Dp[e];
    int l0 = c * CL;
    for (int l = 0; l < CL; ++l) {
        size_t tok = (size_t)b * LSEQ + l0 + l;
        float d = delta_of(dtb, tok, wv, dbias);
        float xcv = bf2f(xcb[tok * DI + e]);
        float zv  = bf2f(xz[tok * 2048 + DI + e]);
        float dx = d * xcv;
        const float4* B4 = (const float4*)(xdbl + tok * 64 + 32);
        const float4* C4 = (const float4*)(xdbl + tok * 64 + 48);
        float yv = 0.0f;
        #pragma unroll
        for (int q = 0; q < 4; ++q) {
            float4 Bq = B4[q];
            float4 Cq = C4[q];
            float hb;
            hb = __expf(d * Ae[4*q+0]) * h[4*q+0] + dx * Bq.x; h[4*q+0] = hb; yv = fmaf(hb, Cq.x, yv);
            hb = __expf(d * Ae[4*q+1]) * h[4*q+1] + dx * Bq.y; h[4*q+1] = hb; yv = fmaf(hb, Cq.y, yv);
            hb = __expf(d * Ae[4*q+2]) * h[4*q+2] + dx * Bq.z; h[4*q+2] = hb; yv = fmaf(hb, Cq.z, yv);
            hb = __expf(d * Ae[4*q+3]) * h[4*q+3] + dx * Bq.w; h[4*q+3] = hb; yv = fmaf(hb, Cq.w, yv);
        }
        yv += xcv * Dv;
        yv *= siluf(zv);
        y[tok * DI + e] = f2bf(yv);
    }
}

extern "C" void kernel_launch(void* const* d_in, const int* in_sizes, int n_in,
                              void* d_out, int out_size, void* d_ws, size_t ws_size,
                              hipStream_t stream)
{
    const float* x         = (const float*)d_in[0];
    const float* ln1_g     = (const float*)d_in[1];
    const float* ln1_b     = (const float*)d_in[2];
    const float* in_proj_w = (const float*)d_in[3];
    const float* conv_w    = (const float*)d_in[4];
    const float* conv_b    = (const float*)d_in[5];
    const float* x_proj_w  = (const float*)d_in[6];
    const float* dt_proj_w = (const float*)d_in[7];
    const float* dt_proj_b = (const float*)d_in[8];
    const float* A_log     = (const float*)d_in[9];
    const float* Dp        = (const float*)d_in[10];
    const float* out_proj_w= (const float*)d_in[11];
    const float* ln2_g     = (const float*)d_in[12];
    const float* ln2_b     = (const float*)d_in[13];
    const float* ffn1_w    = (const float*)d_in[14];
    const float* ffn1_b    = (const float*)d_in[15];
    const float* ffn2_w    = (const float*)d_in[16];
    const float* ffn2_b    = (const float*)d_in[17];
    float* out = (float*)d_out;

    // -------- workspace carve, no aliasing --------
    char* wsb = (char*)d_ws;
    u16*   lnb   = (u16*)wsb;    wsb += (size_t)2048 * 512 * 2;       // 2MB
    u16*   xzb   = (u16*)wsb;    wsb += (size_t)2048 * 2048 * 2;      // 8MB
    u16*   xcb   = (u16*)wsb;    wsb += (size_t)2048 * 1024 * 2;      // 4MB
    float* xdbl  = (float*)wsb;  wsb += (size_t)2048 * 64 * 4;        // 512KB
    u16*   dtb   = (u16*)wsb;    wsb += (size_t)2048 * 32 * 2;        // 128KB
    float* Ppart = (float*)wsb;  wsb += (size_t)8 * 2048 * 64 * 4;    // 4MB
    u16*   qbuf  = (u16*)wsb;    wsb += (size_t)BB * NC * 16 * DI * 2;// 4MB
    float* sumd  = (float*)wsb;  wsb += (size_t)BB * NC * DI * 4;     // 512KB
    u16*   hin   = (u16*)wsb;    wsb += (size_t)BB * NC * 16 * DI * 2;// 4MB
    u16*   ybuf  = (u16*)wsb;    wsb += (size_t)2048 * 1024 * 2;      // 4MB
    float* x2    = (float*)wsb;  wsb += (size_t)2048 * 512 * 4;       // 4MB
    u16*   ffnm  = (u16*)wsb;    wsb += (size_t)2048 * 2048 * 2;      // 8MB
    u16*   w_in  = (u16*)wsb;    wsb += (size_t)2048 * 512 * 2;       // 2MB
    u16*   w_out = (u16*)wsb;    wsb += (size_t)512 * 1024 * 2;       // 1MB
    u16*   w_f1  = (u16*)wsb;    wsb += (size_t)2048 * 512 * 2;       // 2MB
    u16*   w_f2  = (u16*)wsb;    wsb += (size_t)512 * 2048 * 2;       // 2MB
    u16*   w_x   = (u16*)wsb;    wsb += (size_t)64 * 1024 * 2;        // 128KB
    u16*   w_dt  = (u16*)wsb;    wsb += (size_t)1024 * 32 * 2;        // 64KB

    // 0+1) weight conversions + LN1 (fused)
    prep_kernel<<<NCVT + NTOK, 256, 0, stream>>>(in_proj_w, w_in, out_proj_w, w_out,
                                                 ffn1_w, w_f1, ffn2_w, w_f2,
                                                 x_proj_w, w_x, dt_proj_w, w_dt,
                                                 x, ln1_g, ln1_b, lnb);
    // 2) in_proj MFMA 128x64 tile, 512 blocks: -> xz bf16 [2048,2048]
    mgemm_kernel<0,128,64,64,1><<<dim3(32,16), 256, 0, stream>>>(lnb, w_in, 512, xzb, 2048, nullptr, nullptr, 0);
    // 3) FUSED conv+silu + x_proj split-K MFMA -> xcb bf16 + Ppart
    xproj_conv_kernel<<<dim3(8, 32), 256, 0, stream>>>(xzb, conv_w, conv_b, w_x, xcb, Ppart);
    // 4) reduce partials -> xdbl fp32 + dtb bf16
    xproj_reduce_kernel<<<(NTOK * 64) / 256, 256, 0, stream>>>(Ppart, xdbl, dtb);
    // 5) chunked scan, dt_proj inlined (NC=64, CL=16), bf16 e-innermost intermediates
    scanA_kernel<<<(BB * NC * DI) / 256, 256, 0, stream>>>(dtb, w_dt, dt_proj_b, xcb, xdbl, A_log, qbuf, sumd);
    scanB_kernel<<<(BB * 16 * DI) / 256, 256, 0, stream>>>(qbuf, sumd, A_log, hin);
    scanC_kernel<<<(BB * NC * DI) / 256, 256, 0, stream>>>(dtb, w_dt, dt_proj_b, xcb, xdbl, xzb, A_log, Dp, hin, ybuf);
    // 6) out_proj MFMA + residual(x): [2048,1024]x[512,1024]^T -> x2 fp32
    mgemm_kernel<3,64,64,128,0><<<dim3(8,32), 256, 0, stream>>>(ybuf, w_out, 1024, x2, 512, nullptr, x, 512);
    // 7) LN2 -> bf16
    ln_bf16_kernel<<<NTOK, 256, 0, stream>>>(x2, ln2_g, ln2_b, lnb);
    // 8) ffn1 MFMA 128x64 tile + bias + gelu -> ffn_mid bf16 [2048,2048]
    mgemm_kernel<2,128,64,64,1><<<dim3(32,16), 256, 0, stream>>>(lnb, w_f1, 512, ffnm, 2048, ffn1_b, nullptr, 0);
    // 9) ffn2 MFMA + bias + residual(x2) -> out fp32
    mgemm_kernel<4,64,64,128,0><<<dim3(8,32), 256, 0, stream>>>(ffnm, w_f2, 2048, out, 512, ffn2_b, x2, 512);
}

// Round 13
// 162.467 us; speedup vs baseline: 1.4102x; 1.0408x over previous
//
#include <hip/hip_runtime.h>
#include <cmath>

typedef unsigned short u16;
typedef __attribute__((ext_vector_type(8))) short bf16x8;
typedef __attribute__((ext_vector_type(4))) float f32x4;

#define BB    2
#define LSEQ  1024
#define DM    512
#define DI    1024
#define NTOK  2048   // BB*LSEQ
#define NC    64     // chunks per sequence
#define CL    16     // chunk length

__device__ __forceinline__ float siluf(float x) {
    return x * (1.0f / (1.0f + __expf(-x)));
}
__device__ __forceinline__ float geluf(float x) {
    float c = 0.7978845608028654f * (x + 0.044715f * x * x * x);
    return 0.5f * x * (1.0f + tanhf(c));
}
__device__ __forceinline__ u16 f2bf(float f) {
    union { float f; unsigned u; } v; v.f = f;
    unsigned r = v.u + 0x7fff + ((v.u >> 16) & 1);
    return (u16)(r >> 16);
}
__device__ __forceinline__ float bf2f(u16 u) {
    union { unsigned u; float f; } v; v.u = ((unsigned)u) << 16; return v.f;
}
__device__ __forceinline__ void async_cp16(const u16* g, u16* l) {
    __builtin_amdgcn_global_load_lds(
        (const __attribute__((address_space(1))) void*)g,
        (__attribute__((address_space(3))) void*)l, 16, 0, 0);
}

#define NCVT 3680   // blocks for weight conversion (3768320 elems / 1024)

// ---------------- prep: weight bf16 conversion + LN1, one kernel ----------------
__global__ void prep_kernel(const float* __restrict__ s0, u16* __restrict__ d0,   // 1048576 in_proj
                            const float* __restrict__ s1, u16* __restrict__ d1,   // 524288  out_proj
                            const float* __restrict__ s2, u16* __restrict__ d2,   // 1048576 ffn1
                            const float* __restrict__ s3, u16* __restrict__ d3,   // 1048576 ffn2
                            const float* __restrict__ s4, u16* __restrict__ d4,   // 65536   x_proj
                            const float* __restrict__ s5, u16* __restrict__ d5,   // 32768   dt_proj
                            const float* __restrict__ x, const float* __restrict__ g,
                            const float* __restrict__ b, u16* __restrict__ lnb)
{
    __shared__ float shs[4], shq[4];
    __shared__ float smu, srs;
    if (blockIdx.x < NCVT) {
        int i = (blockIdx.x * 256 + threadIdx.x) * 4;
        const float* sp; u16* dp; int off;
        if      (i < 1048576) { sp = s0; dp = d0; off = i; }
        else if (i < 1572864) { sp = s1; dp = d1; off = i - 1048576; }
        else if (i < 2621440) { sp = s2; dp = d2; off = i - 1572864; }
        else if (i < 3670016) { sp = s3; dp = d3; off = i - 2621440; }
        else if (i < 3735552) { sp = s4; dp = d4; off = i - 3670016; }
        else                  { sp = s5; dp = d5; off = i - 3735552; }
        float4 v = *(const float4*)(sp + off);
        ushort4 o;
        o.x = f2bf(v.x); o.y = f2bf(v.y); o.z = f2bf(v.z); o.w = f2bf(v.w);
        *(ushort4*)(dp + off) = o;
        return;
    }
    // LayerNorm branch: token t
    int t = blockIdx.x - NCVT;
    int tid = threadIdx.x;
    const float* xr = x + (size_t)t * DM;
    float v0 = xr[tid];
    float v1 = xr[tid + 256];
    float rsum = v0 + v1;
    float rsq  = v0 * v0 + v1 * v1;
    #pragma unroll
    for (int o = 32; o > 0; o >>= 1) { rsum += __shfl_down(rsum, o); rsq += __shfl_down(rsq, o); }
    int wid = tid >> 6, lane = tid & 63;
    if (lane == 0) { shs[wid] = rsum; shq[wid] = rsq; }
    __syncthreads();
    if (tid == 0) {
        float a  = shs[0] + shs[1] + shs[2] + shs[3];
        float a2 = shq[0] + shq[1] + shq[2] + shq[3];
        float mu = a / DM;
        float var = a2 / DM - mu * mu;
        smu = mu;
        srs = rsqrtf(var + 1e-5f);
    }
    __syncthreads();
    float mu = smu, rs = srs;
    u16* orow = lnb + (size_t)t * DM;
    orow[tid]       = f2bf((v0 - mu) * rs * g[tid]       + b[tid]);
    orow[tid + 256] = f2bf((v1 - mu) * rs * g[tid + 256] + b[tid + 256]);
}

// ---------------- standalone LayerNorm (LN2) ----------------
__global__ void ln_bf16_kernel(const float* __restrict__ x, const float* __restrict__ g,
                               const float* __restrict__ b, u16* __restrict__ out)
{
    int t = blockIdx.x;
    int tid = threadIdx.x;
    const float* xr = x + (size_t)t * DM;
    float v0 = xr[tid];
    float v1 = xr[tid + 256];
    float rsum = v0 + v1;
    float rsq  = v0 * v0 + v1 * v1;
    #pragma unroll
    for (int o = 32; o > 0; o >>= 1) { rsum += __shfl_down(rsum, o); rsq += __shfl_down(rsq, o); }
    __shared__ float shs[4], shq[4];
    __shared__ float smu, srs;
    int wid = tid >> 6, lane = tid & 63;
    if (lane == 0) { shs[wid] = rsum; shq[wid] = rsq; }
    __syncthreads();
    if (tid == 0) {
        float a  = shs[0] + shs[1] + shs[2] + shs[3];
        float a2 = shq[0] + shq[1] + shq[2] + shq[3];
        float mu = a / DM;
        float var = a2 / DM - mu * mu;
        smu = mu;
        srs = rsqrtf(var + 1e-5f);
    }
    __syncthreads();
    float mu = smu, rs = srs;
    u16* orow = out + (size_t)t * DM;
    orow[tid]       = f2bf((v0 - mu) * rs * g[tid]       + b[tid]);
    orow[tid + 256] = f2bf((v1 - mu) * rs * g[tid + 256] + b[tid + 256]);
}

// ---------------- 4-wave MFMA GEMM (generic BMxBN tiles, 2x2 wave grid) ----------------
// EPI: 0 plain, 2 bias+gelu, 3 +resid, 4 bias+resid. OBF: bf16 out.
template<int EPI, int BM, int BN, int BK, int OBF>
__global__ __launch_bounds__(256)
void mgemm_kernel(const u16* __restrict__ A, const u16* __restrict__ W, int K,
                  void* __restrict__ Cp, int ldc,
                  const float* __restrict__ bias, const float* __restrict__ resid, int ldr)
{
    __shared__ u16 As[BM * BK];
    __shared__ u16 Bs[BN * BK];
    constexpr int WR = BM / 2, WC = BN / 2;
    constexpr int MR = WR / 16, NR = WC / 16;
    constexpr int LPR = BK / 8;
    constexpr int CH_ROWS = 64 / LPR;
    constexpr int NCH_A = BM / CH_ROWS, NCH_B = BN / CH_ROWS;

    const int tid = threadIdx.x;
    const int wave = tid >> 6, lane = tid & 63;
    const int wm = wave >> 1, wn = wave & 1;
    const int m0 = blockIdx.y * BM, n0 = blockIdx.x * BN;
    const int crow = lane / LPR, ckoff = (lane % LPR) * 8;
    const int fr = lane & 15;

    f32x4 acc[MR][NR] = {};

    for (int k0 = 0; k0 < K; k0 += BK) {
        for (int c = wave; c < NCH_A; c += 4)
            async_cp16(A + (size_t)(m0 + c * CH_ROWS + crow) * K + k0 + ckoff, &As[c * 512]);
        for (int c = wave; c < NCH_B; c += 4)
            async_cp16(W + (size_t)(n0 + c * CH_ROWS + crow) * K + k0 + ckoff, &Bs[c * 512]);
        __syncthreads();
        #pragma unroll
        for (int ks = 0; ks < BK / 32; ++ks) {
            const int fk = ks * 32 + ((lane >> 4) << 3);
            bf16x8 af[MR], bv[NR];
            #pragma unroll
            for (int i = 0; i < MR; ++i)
                af[i] = *(const bf16x8*)&As[(wm * WR + i * 16 + fr) * BK + fk];
            #pragma unroll
            for (int j = 0; j < NR; ++j)
                bv[j] = *(const bf16x8*)&Bs[(wn * WC + j * 16 + fr) * BK + fk];
            #pragma unroll
            for (int i = 0; i < MR; ++i)
                #pragma unroll
                for (int j = 0; j < NR; ++j)
                    acc[i][j] = __builtin_amdgcn_mfma_f32_16x16x32_bf16(af[i], bv[j], acc[i][j], 0, 0, 0);
        }
        __syncthreads();
    }

    const int rbase = (lane >> 4) << 2;
    #pragma unroll
    for (int i = 0; i < MR; ++i) {
        #pragma unroll
        for (int j = 0; j < NR; ++j) {
            const int col  = n0 + wn * WC + j * 16 + fr;
            const int row0 = m0 + wm * WR + i * 16 + rbase;
            float bvv = (EPI == 2 || EPI == 4) ? bias[col] : 0.0f;
            #pragma unroll
            for (int r = 0; r < 4; ++r) {
                float v = acc[i][j][r];
                if (EPI == 2) v = geluf(v + bvv);
                if (EPI == 3) v += resid[(size_t)(row0 + r) * ldr + col];
                if (EPI == 4) v += bvv + resid[(size_t)(row0 + r) * ldr + col];
                if (OBF) ((u16*)Cp)[(size_t)(row0 + r) * ldc + col] = f2bf(v);
                else     ((float*)Cp)[(size_t)(row0 + r) * ldc + col] = v;
            }
        }
    }
}

// ---------------- FUSED conv+SiLU + x_proj split-K MFMA ----------------
// Block (ks, mb): computes conv+silu for tokens m0..m0+63, channels k0..k0+127
// directly into its LDS A-tile (and to xcb global for the scans), then does the
// 64x64x128 MFMA against x_proj weights. P[ks][2048][64] partials out.
__global__ __launch_bounds__(256)
void xproj_conv_kernel(const u16* __restrict__ xz,      // [NTOK,2048] bf16
                       const float* __restrict__ cw, const float* __restrict__ cb,
                       const u16* __restrict__ wx,      // [64,1024] bf16
                       u16* __restrict__ xcb,           // [NTOK,DI] bf16 out
                       float* __restrict__ P)
{
    constexpr int BM = 64, BK = 128;
    __shared__ u16 As[BM * BK];
    __shared__ u16 Bs[64 * BK];
    const int tid = threadIdx.x;
    const int wave = tid >> 6, lane = tid & 63;
    const int wm = wave >> 1, wn = wave & 1;
    const int ks = blockIdx.x;               // 0..7
    const int m0 = blockIdx.y * BM;
    const int k0 = ks * BK;
    const int fr = lane & 15;

    // stage B (x_proj weights) via global_load_lds
    {
        const int crow = lane >> 4, ckoff = (lane & 15) * 8;
        for (int c = wave; c < 16; c += 4)
            async_cp16(wx + (size_t)(c * 4 + crow) * 1024 + k0 + ckoff, &Bs[c * 512]);
    }
    // conv + silu into A-tile (LDS) + xcb (global). 8 ch/thread, 4 iters.
    #pragma unroll
    for (int it = tid; it < BM * (BK / 8); it += 256) {
        const int row = it >> 4;             // 0..63 (token within tile)
        const int c8  = it & 15;             // 0..15 (channel-octet)
        const int e   = k0 + c8 * 8;
        const int t   = m0 + row;
        const int l   = t & (LSEQ - 1);
        const u16* base = xz + (size_t)t * 2048 + e;
        bf16x8 r0 = {}, r1 = {}, r2 = {}, r3;
        r3 = *(const bf16x8*)(base);
        if (l >= 1) r2 = *(const bf16x8*)(base - 2048);
        if (l >= 2) r1 = *(const bf16x8*)(base - 2 * 2048);
        if (l >= 3) r0 = *(const bf16x8*)(base - 3 * 2048);
        bf16x8 obf;
        #pragma unroll
        for (int j = 0; j < 8; ++j) {
            const float4 w = *(const float4*)(cw + (e + j) * 4);
            float acc = cb[e + j];
            acc = fmaf(bf2f((u16)r0[j]), w.x, acc);
            acc = fmaf(bf2f((u16)r1[j]), w.y, acc);
            acc = fmaf(bf2f((u16)r2[j]), w.z, acc);
            acc = fmaf(bf2f((u16)r3[j]), w.w, acc);
            obf[j] = (short)f2bf(siluf(acc));
        }
        *(bf16x8*)&As[row * BK + c8 * 8] = obf;
        *(bf16x8*)(xcb + (size_t)t * DI + e) = obf;
    }
    __syncthreads();   // drains lgkm (LDS writes) + vm (global_load_lds)

    f32x4 acc[2][2] = {};
    #pragma unroll
    for (int ks2 = 0; ks2 < 4; ++ks2) {
        const int fk = ks2 * 32 + ((lane >> 4) << 3);
        bf16x8 af[2], bv[2];
        #pragma unroll
        for (int i = 0; i < 2; ++i)
            af[i] = *(const bf16x8*)&As[(wm * 32 + i * 16 + fr) * BK + fk];
        #pragma unroll
        for (int j = 0; j < 2; ++j)
            bv[j] = *(const bf16x8*)&Bs[(wn * 32 + j * 16 + fr) * BK + fk];
        #pragma unroll
        for (int i = 0; i < 2; ++i)
            #pragma unroll
            for (int j = 0; j < 2; ++j)
                acc[i][j] = __builtin_amdgcn_mfma_f32_16x16x32_bf16(af[i], bv[j], acc[i][j], 0, 0, 0);
    }

    const int rbase = (lane >> 4) << 2;
    float* Pk = P + (size_t)ks * NTOK * 64;
    #pragma unroll
    for (int i = 0; i < 2; ++i)
        #pragma unroll
        for (int j = 0; j < 2; ++j) {
            const int col  = wn * 32 + j * 16 + fr;
            const int row0 = m0 + wm * 32 + i * 16 + rbase;
            #pragma unroll
            for (int r = 0; r < 4; ++r)
                Pk[(size_t)(row0 + r) * 64 + col] = acc[i][j][r];
        }
}

// reduce partials -> xdbl fp32 [2048,64]; also emit dt columns (0..31) as bf16 [2048,32]
__global__ void xproj_reduce_kernel(const float* __restrict__ P, float* __restrict__ xdbl,
                                    u16* __restrict__ dtb)
{
    int i = blockIdx.x * 256 + threadIdx.x;   // over 2048*64
    float s = 0.0f;
    #pragma unroll
    for (int ks = 0; ks < 8; ++ks) s += P[(size_t)ks * NTOK * 64 + i];
    xdbl[i] = s;
    int col = i & 63;
    if (col < 32) dtb[(i >> 6) * 32 + col] = f2bf(s);
}

// ---- inline dt_proj + softplus: delta for one (tok, e). dtb row is wave-uniform ----
__device__ __forceinline__ float delta_of(const u16* __restrict__ dtb, size_t tok,
                                          const bf16x8* wv, float dbias)
{
    float dt = dbias;
    const u16* dr = dtb + tok * 32;
    #pragma unroll
    for (int q = 0; q < 4; ++q) {
        bf16x8 dv = *(const bf16x8*)(dr + q * 8);
        #pragma unroll
        for (int k = 0; k < 8; ++k)
            dt = fmaf(bf2f((u16)dv[k]), bf2f((u16)wv[q][k]), dt);
    }
    return (dt < 20.0f) ? log1pf(__expf(dt)) : dt;
}

// ============ chunked selective scan (NC=64, CL=16); dt_proj inlined ============
// Layouts (e innermost => all accesses wave-coalesced):
//   qbuf[((b*NC+c)*16+n)*DI + e]  bf16
//   hin [((b*NC+c)*16+n)*DI + e]  bf16
//   sumd[(b*NC+c)*DI + e]         fp32
__global__ void scanA_kernel(const u16* __restrict__ dtb,
                             const u16* __restrict__ wdt,
                             const float* __restrict__ dt_bias,
                             const u16* __restrict__ xcb,
                             const float* __restrict__ xdbl,
                             const float* __restrict__ A_log,
                             u16* __restrict__ qbuf,
                             float* __restrict__ sumd)
{
    int i = blockIdx.x * 256 + threadIdx.x;   // ((b*NC + c) << 10) | e
    int e = i & (DI - 1);
    int bc = i >> 10;                          // b*NC + c
    int c = bc & (NC - 1);
    int b = bc >> 6;
    float Ae[16], h[16];
    #pragma unroll
    for (int n = 0; n < 16; ++n) { Ae[n] = -__expf(A_log[e * 16 + n]); h[n] = 0.0f; }
    const float dbias = dt_bias[e];
    bf16x8 wv[4];
    #pragma unroll
    for (int q = 0; q < 4; ++q) wv[q] = *(const bf16x8*)(wdt + e * 32 + q * 8);
    float sd = 0.0f;
    int l0 = c * CL;
    for (int l = 0; l < CL; ++l) {
        size_t tok = (size_t)b * LSEQ + l0 + l;
        float d = delta_of(dtb, tok, wv, dbias);
        float xcv = bf2f(xcb[tok * DI + e]);
        sd += d;
        float dx = d * xcv;
        const float4* B4 = (const float4*)(xdbl + tok * 64 + 32);
        #pragma unroll
        for (int q = 0; q < 4; ++q) {
            float4 Bq = B4[q];
            h[4*q+0] = __expf(d * Ae[4*q+0]) * h[4*q+0] + dx * Bq.x;
            h[4*q+1] = __expf(d * Ae[4*q+1]) * h[4*q+1] + dx * Bq.y;
            h[4*q+2] = __expf(d * Ae[4*q+2]) * h[4*q+2] + dx * Bq.z;
            h[4*q+3] = __expf(d * Ae[4*q+3]) * h[4*q+3] + dx * Bq.w;
        }
    }
    size_t qbase = (size_t)bc * 16 * DI + e;
    #pragma unroll
    for (int n = 0; n < 16; ++n) qbuf[qbase + (size_t)n * DI] = f2bf(h[n]);
    sumd[(size_t)bc * DI + e] = sd;
}

__global__ void scanB_kernel(const u16* __restrict__ qbuf,
                             const float* __restrict__ sumd,
                             const float* __restrict__ A_log,
                             u16* __restrict__ hin)
{
    int i = blockIdx.x * 256 + threadIdx.x;   // ((b*16 + n) << 10) | e
    int e = i & (DI - 1);
    int bn = i >> 10;
    int n = bn & 15;
    int b = bn >> 4;
    float Ae = -__expf(A_log[e * 16 + n]);
    float h = 0.0f;
    for (int c = 0; c < NC; ++c) {
        size_t idx = ((size_t)((b * NC + c) * 16 + n)) * DI + e;
        hin[idx] = f2bf(h);
        float P = __expf(Ae * sumd[(size_t)(b * NC + c) * DI + e]);
        h = P * h + bf2f(qbuf[idx]);
    }
}

// Pass C: replay from entry state; y (bf16) = (scan + xc*D) * silu(z)
__global__ void scanC_kernel(const u16* __restrict__ dtb,
                             const u16* __restrict__ wdt,
                             const float* __restrict__ dt_bias,
                             const u16* __restrict__ xcb,
                             const float* __restrict__ xdbl,
                             const u16* __restrict__ xz,
                             const float* __restrict__ A_log,
                             const float* __restrict__ Dp,
                             const u16* __restrict__ hin,
                             u16* __restrict__ y)
{
    int i = blockIdx.x * 256 + threadIdx.x;
    int e = i & (DI - 1);
    int bc = i >> 10;
    int c = bc & (NC - 1);
    int b = bc >> 6;
    float Ae[16], h[16];
    size_t hbase = (size_t)bc * 16 * DI + e;
    #pragma unroll
    for (int n = 0; n < 16; ++n) {
        Ae[n] = -__expf(A_log[e * 16 + n]);
        h[n] = bf2f(hin[hbase + (size_t)n * DI]);
    }
    const float dbias = dt_bias[e];
    bf16x8 wv[4];
    #pragma unroll
    for (int q = 0; q < 4; ++q) wv[q] = *(const bf16x8*)(wdt + e * 32 + q * 8);
    float Dv = Dp[e];
    int l0 = c * CL;
    for (int l = 0; l < CL; ++l) {
        size_t tok = (size_t)b * LSEQ + l0 + l;
        float d = delta_of(dtb, tok, wv, dbias);
        float xcv = bf2f(xcb[tok * DI + e]);
        float zv  = bf2f(xz[tok * 2048 + DI + e]);
        float dx = d * xcv;
        const float4* B4 = (const float4*)(xdbl + tok * 64 + 32);
        const float4* C4 = (const float4*)(xdbl + tok * 64 + 48);
        float yv = 0.0f;
        #pragma unroll
        for (int q = 0; q < 4; ++q) {
            float4 Bq = B4[q];
            float4 Cq = C4[q];
            float hb;
            hb = __expf(d * Ae[4*q+0]) * h[4*q+0] + dx * Bq.x; h[4*q+0] = hb; yv = fmaf(hb, Cq.x, yv);
            hb = __expf(d * Ae[4*q+1]) * h[4*q+1] + dx * Bq.y; h[4*q+1] = hb; yv = fmaf(hb, Cq.y, yv);
            hb = __expf(d * Ae[4*q+2]) * h[4*q+2] + dx * Bq.z; h[4*q+2] = hb; yv = fmaf(hb, Cq.z, yv);
            hb = __expf(d * Ae[4*q+3]) * h[4*q+3] + dx * Bq.w; h[4*q+3] = hb; yv = fmaf(hb, Cq.w, yv);
        }
        yv += xcv * Dv;
        yv *= siluf(zv);
        y[tok * DI + e] = f2bf(yv);
    }
}

extern "C" void kernel_launch(void* const* d_in, const int* in_sizes, int n_in,
                              void* d_out, int out_size, void* d_ws, size_t ws_size,
                              hipStream_t stream)
{
    const float* x         = (const float*)d_in[0];
    const float* ln1_g     = (const float*)d_in[1];
    const float* ln1_b     = (const float*)d_in[2];
    const float* in_proj_w = (const float*)d_in[3];
    const float* conv_w    = (const float*)d_in[4];
    const float* conv_b    = (const float*)d_in[5];
    const float* x_proj_w  = (const float*)d_in[6];
    const float* dt_proj_w = (const float*)d_in[7];
    const float* dt_proj_b = (const float*)d_in[8];
    const float* A_log     = (const float*)d_in[9];
    const float* Dp        = (const float*)d_in[10];
    const float* out_proj_w= (const float*)d_in[11];
    const float* ln2_g     = (const float*)d_in[12];
    const float* ln2_b     = (const float*)d_in[13];
    const float* ffn1_w    = (const float*)d_in[14];
    const float* ffn1_b    = (const float*)d_in[15];
    const float* ffn2_w    = (const float*)d_in[16];
    const float* ffn2_b    = (const float*)d_in[17];
    float* out = (float*)d_out;

    // -------- workspace carve, no aliasing --------
    char* wsb = (char*)d_ws;
    u16*   lnb   = (u16*)wsb;    wsb += (size_t)2048 * 512 * 2;       // 2MB
    u16*   xzb   = (u16*)wsb;    wsb += (size_t)2048 * 2048 * 2;      // 8MB
    u16*   xcb   = (u16*)wsb;    wsb += (size_t)2048 * 1024 * 2;      // 4MB
    float* xdbl  = (float*)wsb;  wsb += (size_t)2048 * 64 * 4;        // 512KB
    u16*   dtb   = (u16*)wsb;    wsb += (size_t)2048 * 32 * 2;        // 128KB
    float* Ppart = (float*)wsb;  wsb += (size_t)8 * 2048 * 64 * 4;    // 4MB
    u16*   qbuf  = (u16*)wsb;    wsb += (size_t)BB * NC * 16 * DI * 2;// 4MB
    float* sumd  = (float*)wsb;  wsb += (size_t)BB * NC * DI * 4;     // 512KB
    u16*   hin   = (u16*)wsb;    wsb += (size_t)BB * NC * 16 * DI * 2;// 4MB
    u16*   ybuf  = (u16*)wsb;    wsb += (size_t)2048 * 1024 * 2;      // 4MB
    float* x2    = (float*)wsb;  wsb += (size_t)2048 * 512 * 4;       // 4MB
    u16*   ffnm  = (u16*)wsb;    wsb += (size_t)2048 * 2048 * 2;      // 8MB
    u16*   w_in  = (u16*)wsb;    wsb += (size_t)2048 * 512 * 2;       // 2MB
    u16*   w_out = (u16*)wsb;    wsb += (size_t)512 * 1024 * 2;       // 1MB
    u16*   w_f1  = (u16*)wsb;    wsb += (size_t)2048 * 512 * 2;       // 2MB
    u16*   w_f2  = (u16*)wsb;    wsb += (size_t)512 * 2048 * 2;       // 2MB
    u16*   w_x   = (u16*)wsb;    wsb += (size_t)64 * 1024 * 2;        // 128KB
    u16*   w_dt  = (u16*)wsb;    wsb += (size_t)1024 * 32 * 2;        // 64KB

    // 0+1) weight conversions + LN1 (fused)
    prep_kernel<<<NCVT + NTOK, 256, 0, stream>>>(in_proj_w, w_in, out_proj_w, w_out,
                                                 ffn1_w, w_f1, ffn2_w, w_f2,
                                                 x_proj_w, w_x, dt_proj_w, w_dt,
                                                 x, ln1_g, ln1_b, lnb);
    // 2) in_proj MFMA 128x64 tile, 512 blocks: -> xz bf16 [2048,2048]
    mgemm_kernel<0,128,64,64,1><<<dim3(32,16), 256, 0, stream>>>(lnb, w_in, 512, xzb, 2048, nullptr, nullptr, 0);
    // 3) FUSED conv+silu + x_proj split-K MFMA -> xcb bf16 + Ppart
    xproj_conv_kernel<<<dim3(8, 32), 256, 0, stream>>>(xzb, conv_w, conv_b, w_x, xcb, Ppart);
    // 4) reduce partials -> xdbl fp32 + dtb bf16
    xproj_reduce_kernel<<<(NTOK * 64) / 256, 256, 0, stream>>>(Ppart, xdbl, dtb);
    // 5) chunked scan, dt_proj inlined (NC=64, CL=16), bf16 e-innermost intermediates
    scanA_kernel<<<(BB * NC * DI) / 256, 256, 0, stream>>>(dtb, w_dt, dt_proj_b, xcb, xdbl, A_log, qbuf, sumd);
    scanB_kernel<<<(BB * 16 * DI) / 256, 256, 0, stream>>>(qbuf, sumd, A_log, hin);
    scanC_kernel<<<(BB * NC * DI) / 256, 256, 0, stream>>>(dtb, w_dt, dt_proj_b, xcb, xdbl, xzb, A_log, Dp, hin, ybuf);
    // 6) out_proj MFMA 64x32 tile (512 blocks) + residual(x): -> x2 fp32
    mgemm_kernel<3,64,32,128,0><<<dim3(16,32), 256, 0, stream>>>(ybuf, w_out, 1024, x2, 512, nullptr, x, 512);
    // 7) LN2 -> bf16
    ln_bf16_kernel<<<NTOK, 256, 0, stream>>>(x2, ln2_g, ln2_b, lnb);
    // 8) ffn1 MFMA 128x64 tile + bias + gelu -> ffn_mid bf16 [2048,2048]
    mgemm_kernel<2,128,64,64,1><<<dim3(32,16), 256, 0, stream>>>(lnb, w_f1, 512, ffnm, 2048, ffn1_b, nullptr, 0);
    // 9) ffn2 MFMA 64x32 tile (512 blocks) + bias + residual(x2) -> out fp32
    mgemm_kernel<4,64,32,128,0><<<dim3(16,32), 256, 0, stream>>>(ffnm, w_f2, 2048, out, 512, ffn2_b, x2, 512);
}